// Round 4
// baseline (241.250 us; speedup 1.0000x reference)
//
#include <hip/hip_runtime.h>
#include <hip/hip_bf16.h>
#include <math.h>

// Problem constants
#define F_DIM 2048
#define B_DIM 2
#define H_DIM 1024
#define N_HEADS 16
#define E_DIM 64
#define D3 3072          // 3*H
#define M_DIM 4096       // F*B

typedef __hip_bfloat16 bf16;
typedef __attribute__((ext_vector_type(8))) __bf16 bf16x8;
typedef __attribute__((ext_vector_type(8))) unsigned short u16x8;
typedef __attribute__((ext_vector_type(4))) float f32x4;

// float -> bf16 bits, round-to-nearest-even
static __device__ __forceinline__ unsigned short f2bf(float f) {
    unsigned u = __float_as_uint(f);
    return (unsigned short)((u + 0x7FFFu + ((u >> 16) & 1u)) >> 16);
}

// pack two floats to bf16x2 (RNE); HW packed convert when available
static __device__ __forceinline__ unsigned pk_bf16(float a, float b) {
#if __has_builtin(__builtin_amdgcn_cvt_pk_bf16_f32)
    typedef __attribute__((ext_vector_type(2))) __bf16 bf16x2;
    bf16x2 v = __builtin_amdgcn_cvt_pk_bf16_f32(a, b);
    unsigned u; __builtin_memcpy(&u, &v, 4); return u;
#else
    return (unsigned)f2bf(a) | ((unsigned)f2bf(b) << 16);
#endif
}

// async global->LDS, 16B per lane; lds ptr must be wave-uniform base
static __device__ __forceinline__ void glds16(const unsigned short* g, unsigned short* l) {
    __builtin_amdgcn_global_load_lds((const __attribute__((address_space(1))) unsigned int*)g,
                                     (__attribute__((address_space(3))) unsigned int*)l,
                                     16, 0, 0);
}

// 0.125 * log2(e): folded into q at QKV-gemm epilogue so softmax is exp2(S)
#define Q_SCALE 0.18033688011112042f

// ---------------------------------------------------------------------------
// Fused prep (R10-proven)
// ---------------------------------------------------------------------------
__global__ __launch_bounds__(256) void prep_kernel(const float* __restrict__ q_input,
                                                   const void* __restrict__ mask,
                                                   const float* __restrict__ w_qkv,
                                                   const float* __restrict__ w_out,
                                                   const float* __restrict__ b_out,
                                                   unsigned short* __restrict__ qin_bf,
                                                   unsigned short* __restrict__ wqkv_bt,
                                                   unsigned short* __restrict__ wout_bt,
                                                   unsigned* __restrict__ mbits,
                                                   float* __restrict__ bout_dst) {
    __shared__ float sh[32 * 33];
    const int bid = blockIdx.x;
    const int tid = threadIdx.x;

    if (bid < 2048) {                       // convert
        int i = (bid * 256 + tid) * 8;
        float4 a = *(const float4*)&q_input[i];
        float4 b = *(const float4*)&q_input[i + 4];
        u16x8 o;
        o[0] = f2bf(a.x); o[1] = f2bf(a.y); o[2] = f2bf(a.z); o[3] = f2bf(a.w);
        o[4] = f2bf(b.x); o[5] = f2bf(b.y); o[6] = f2bf(b.z); o[7] = f2bf(b.w);
        *(u16x8*)&qin_bf[i] = o;
    } else if (bid < 6144) {                // transposes
        const float* in; unsigned short* out; int R, C, bx, by;
        if (bid < 5120) { int idx = bid - 2048; in = w_qkv; out = wqkv_bt; R = 1024; C = 3072; bx = idx % 96; by = idx / 96; }
        else            { int idx = bid - 5120; in = w_out; out = wout_bt; R = 1024; C = 1024; bx = idx % 32; by = idx / 32; }
        float (*t)[33] = (float(*)[33])sh;
        const int c0 = bx * 32, r0 = by * 32;
        const int lc = tid & 31, lr = tid >> 5;
        #pragma unroll
        for (int i = 0; i < 4; ++i) {
            int r = lr + i * 8;
            t[r][lc] = in[(size_t)(r0 + r) * C + c0 + lc];
        }
        __syncthreads();
        #pragma unroll
        for (int i = 0; i < 4; ++i) {
            int r = lr + i * 8;
            out[(size_t)(c0 + r) * R + r0 + lc] = f2bf(t[lc][r]);
        }
    } else if (bid < 7168) {                // mask pack with inline detect
        int* shi = (int*)sh;
        int v = ((const int*)mask)[tid] & ~1;
        unsigned long long bal = __ballot(v != 0);
        if ((tid & 63) == 0) shi[tid >> 6] = (bal != 0) ? 1 : 0;
        __syncthreads();
        const int byte_mode = shi[0] | shi[1] | shi[2] | shi[3];
        int w = (bid - 6144) * 256 + tid;
        size_t base = (size_t)w * 32;
        unsigned out = 0;
        if (byte_mode) {
            const unsigned char* mu = (const unsigned char*)mask;
            #pragma unroll
            for (int j = 0; j < 32; ++j) out |= (mu[base + j] ? 1u : 0u) << j;
        } else {
            const int* mi = (const int*)mask;
            #pragma unroll
            for (int j = 0; j < 32; ++j) out |= (mi[base + j] ? 1u : 0u) << j;
        }
        mbits[w] = out;
    } else {                                // b_out copy
        int h = (bid - 7168) * 256 + tid;
        if (h < H_DIM) bout_dst[h] = b_out[h];
    }
}

// --------------------- fallback prep kernels (R9-proven) -------------------
__global__ void detect_mask_kernel(const int* __restrict__ mask_words, int* __restrict__ flag) {
    __shared__ int red[256];
    int v = mask_words[threadIdx.x];
    red[threadIdx.x] = v & ~1;
    __syncthreads();
    for (int s = 128; s > 0; s >>= 1) {
        if (threadIdx.x < s) red[threadIdx.x] |= red[threadIdx.x + s];
        __syncthreads();
    }
    if (threadIdx.x == 0) *flag = (red[0] != 0) ? 1 : 0;
}

__global__ void pack_mask_kernel(const int* __restrict__ mi, const unsigned char* __restrict__ mu,
                                 const int* __restrict__ flag, unsigned* __restrict__ bits) {
    int w = blockIdx.x * 256 + threadIdx.x;
    size_t base = (size_t)w * 32;
    unsigned out = 0;
    if (*flag) {
        #pragma unroll
        for (int j = 0; j < 32; ++j) out |= (mu[base + j] ? 1u : 0u) << j;
    } else {
        #pragma unroll
        for (int j = 0; j < 32; ++j) out |= (mi[base + j] ? 1u : 0u) << j;
    }
    bits[w] = out;
}

__global__ __launch_bounds__(256) void convert_kernel(const float* __restrict__ in,
                                                      unsigned short* __restrict__ out) {
    int i = (blockIdx.x * 256 + threadIdx.x) * 8;
    float4 a = *(const float4*)&in[i];
    float4 b = *(const float4*)&in[i + 4];
    u16x8 o;
    o[0] = f2bf(a.x); o[1] = f2bf(a.y); o[2] = f2bf(a.z); o[3] = f2bf(a.w);
    o[4] = f2bf(b.x); o[5] = f2bf(b.y); o[6] = f2bf(b.z); o[7] = f2bf(b.w);
    *(u16x8*)&out[i] = o;
}

__global__ __launch_bounds__(256) void transpose_bf16_kernel(const float* __restrict__ in,
                                                             unsigned short* __restrict__ out,
                                                             int R, int C) {
    __shared__ float t[32][33];
    const int c0 = blockIdx.x * 32, r0 = blockIdx.y * 32;
    const int lc = threadIdx.x & 31, lr = threadIdx.x >> 5;
    #pragma unroll
    for (int i = 0; i < 4; ++i) {
        int r = lr + i * 8;
        t[r][lc] = in[(size_t)(r0 + r) * C + c0 + lc];
    }
    __syncthreads();
    #pragma unroll
    for (int i = 0; i < 4; ++i) {
        int r = lr + i * 8;
        out[(size_t)(c0 + r) * R + r0 + lc] = f2bf(t[lc][r]);
    }
}

__global__ void bout_copy_kernel(const float* __restrict__ b_out, float* __restrict__ dst) {
    int h = blockIdx.x * 256 + threadIdx.x;
    if (h < H_DIM) dst[h] = b_out[h];
}

// ---------------------------------------------------------------------------
// m97-style bf16 MFMA GEMM, B-transposed input, tile BM x BN (mult of 64).
// SCALE_Q: multiply q-columns (col%192 < 64) by Q_SCALE in the epilogue
// (folds the attention 1/sqrt(E) and log2(e) into Q once).
// ---------------------------------------------------------------------------
template<int BM, int BN, bool ADD_BIAS, bool OUT_BF16, bool SCALE_Q>
__global__ __launch_bounds__(256) void gemm_bt_kernel(const unsigned short* __restrict__ A,
                                                      const unsigned short* __restrict__ Bt,
                                                      const float* __restrict__ bias,
                                                      void* __restrict__ Cout, int Nc) {
    __shared__ unsigned short Ald[BM * 32];
    __shared__ unsigned short Bld[BN * 32];
    constexpr int WM = BM / 2, WN = BN / 2;
    constexpr int MI = WM / 16, NI = WN / 16;
    constexpr int ACH = BM * 4;
    constexpr int TCH = (BM + BN) * 4;
    const int tid = threadIdx.x;
    const int wave = tid >> 6;
    const int lane = tid & 63;
    const int quad = lane >> 4;
    const int l16 = lane & 15;
    const int wm = (wave & 1) * WM;
    const int wn = (wave >> 1) * WN;
    const int m0 = blockIdx.y * BM;
    const int n0 = blockIdx.x * BN;

    f32x4 acc[MI][NI];
    #pragma unroll
    for (int i = 0; i < MI; ++i)
        #pragma unroll
        for (int j = 0; j < NI; ++j) acc[i][j] = (f32x4){0.f, 0.f, 0.f, 0.f};

    for (int k0 = 0; k0 < 1024; k0 += 32) {
        __syncthreads();
        #pragma unroll
        for (int rr = 0; rr < TCH / 256; ++rr) {
            const int chunk = rr * 256 + tid;
            const int wbase = (rr * 256 + wave * 64) * 8;
            if (chunk < ACH) {
                const int row = chunk >> 2, ko = (chunk & 3) * 8;
                glds16(&A[(size_t)(m0 + row) * 1024 + k0 + ko], &Ald[wbase]);
            } else {
                const int c2 = chunk - ACH;
                const int row = c2 >> 2, ko = (c2 & 3) * 8;
                glds16(&Bt[(size_t)(n0 + row) * 1024 + k0 + ko], &Bld[wbase - ACH * 8]);
            }
        }
        __syncthreads();

        bf16x8 af[MI], bfr[NI];
        #pragma unroll
        for (int i = 0; i < MI; ++i)
            af[i] = *(const bf16x8*)&Ald[(wm + i * 16 + l16) * 32 + quad * 8];
        #pragma unroll
        for (int j = 0; j < NI; ++j)
            bfr[j] = *(const bf16x8*)&Bld[(wn + j * 16 + l16) * 32 + quad * 8];
        #pragma unroll
        for (int mi = 0; mi < MI; ++mi)
            #pragma unroll
            for (int ni = 0; ni < NI; ++ni)
                acc[mi][ni] = __builtin_amdgcn_mfma_f32_16x16x32_bf16(af[mi], bfr[ni], acc[mi][ni], 0, 0, 0);
    }

    #pragma unroll
    for (int ni = 0; ni < NI; ++ni) {
        const int col = n0 + wn + ni * 16 + l16;
        const float bv = ADD_BIAS ? bias[col] : 0.f;
        const bool scale = SCALE_Q && ((col % 192) < 64);
        #pragma unroll
        for (int mi = 0; mi < MI; ++mi) {
            const int rowb = m0 + wm + mi * 16 + quad * 4;
            #pragma unroll
            for (int r = 0; r < 4; ++r) {
                float v = acc[mi][ni][r] + bv;
                if (SCALE_Q) v = scale ? v * Q_SCALE : v;
                if (OUT_BF16) ((unsigned short*)Cout)[(size_t)(rowb + r) * Nc + col] = f2bf(v);
                else          ((float*)Cout)[(size_t)(rowb + r) * Nc + col] = v;
            }
        }
    }
}

// ---------------------------------------------------------------------------
// MFMA flash attention (R10-proven structure), fixed-max softmax with the
// scale pre-folded into Q (exp2(S) directly). 128 Q-rows/block, 512 threads.
// R12: s_setprio(1) around both MFMA clusters (T5: +4-7% attn in isolation,
// m191; null/negative on lockstep GEMM m190 so GEMMs left untouched).
// ---------------------------------------------------------------------------
#define LSTR 72        // LDS row stride (elements) for K, Vt, and P
__global__ __launch_bounds__(512) void attn_mfma_kernel(const bf16* __restrict__ qkv_,
                                                        const unsigned* __restrict__ mbits,
                                                        unsigned short* __restrict__ ctxb) {
    __shared__ unsigned short K_lds[64 * LSTR];        // [t][e]      9216 B
    __shared__ unsigned short Vt_lds[64 * LSTR];       // [e][slot]   9216 B
    __shared__ unsigned short P_lds[128 * LSTR];       // [row][slot] 18432 B

    const unsigned short* qkv = (const unsigned short*)qkv_;
    const int tid = threadIdx.x;
    const int wave = tid >> 6;          // 0..7
    const int lane = tid & 63;
    const int quad = lane >> 4;
    const int l16 = lane & 15;
    const int f0 = blockIdx.x * 128;
    const int b = blockIdx.y >> 4;
    const int n = blockIdx.y & 15;
    const int head = n * 192;

    // Q fragments [ks] (A layout): rows f0 + wave*16 + l16 (pre-scaled)
    bf16x8 qf[2];
    #pragma unroll
    for (int ks = 0; ks < 2; ++ks) {
        int f = f0 + wave * 16 + l16;
        qf[ks] = *(const bf16x8*)&qkv[(size_t)(f * B_DIM + b) * D3 + head + ks * 32 + quad * 8];
    }

    f32x4 O[4];
    #pragma unroll
    for (int ec = 0; ec < 4; ++ec) O[ec] = (f32x4){0.f, 0.f, 0.f, 0.f};
    float lsum[4] = {0.f, 0.f, 0.f, 0.f};

    unsigned short* Pw = P_lds + wave * 16 * LSTR;

    for (int t0 = 0; t0 < F_DIM; t0 += 64) {
        __syncthreads();   // previous tile's LDS reads complete

        // stage K tile [64][64] row-major: 512 chunks, 1/thread
        {
            int tr = tid >> 3, e0 = (tid & 7) * 8;
            u16x8 kv = *(const u16x8*)&qkv[(size_t)((t0 + tr) * B_DIM + b) * D3 + head + 64 + e0];
            *(u16x8*)&K_lds[tr * LSTR + e0] = kv;
        }
        // stage V transposed with (t, t+16) interleave: slot h*32+2u(+o).
        if (tid < 256) {
            int u = tid & 15, h = (tid >> 4) & 1, e0 = (tid >> 5) * 8;
            int ta = t0 + h * 32 + u;
            u16x8 v0 = *(const u16x8*)&qkv[(size_t)(ta * B_DIM + b) * D3 + head + 128 + e0];
            u16x8 v1 = *(const u16x8*)&qkv[(size_t)((ta + 16) * B_DIM + b) * D3 + head + 128 + e0];
            #pragma unroll
            for (int j = 0; j < 8; ++j) {
                unsigned pk = (unsigned)v0[j] | ((unsigned)v1[j] << 16);
                *(unsigned*)&Vt_lds[(e0 + j) * LSTR + h * 32 + 2 * u] = pk;
            }
        }
        __syncthreads();   // staging visible

        // S = Q . K^T  [16 x 64] per wave; S[ck] covers t = ck*16 + l16
        f32x4 S[4];
        #pragma unroll
        for (int ck = 0; ck < 4; ++ck) S[ck] = (f32x4){0.f, 0.f, 0.f, 0.f};
        __builtin_amdgcn_s_setprio(1);
        #pragma unroll
        for (int ck = 0; ck < 4; ++ck) {
            bf16x8 kb0 = *(const bf16x8*)&K_lds[(ck * 16 + l16) * LSTR + quad * 8];
            bf16x8 kb1 = *(const bf16x8*)&K_lds[(ck * 16 + l16) * LSTR + 32 + quad * 8];
            S[ck] = __builtin_amdgcn_mfma_f32_16x16x32_bf16(qf[0], kb0, S[ck], 0, 0, 0);
            S[ck] = __builtin_amdgcn_mfma_f32_16x16x32_bf16(qf[1], kb1, S[ck], 0, 0, 0);
        }
        __builtin_amdgcn_s_setprio(0);

        // fixed-max softmax: p = mask ? exp2(S) : 0 (scale folded into Q);
        // packed P writes: (p0,p1) -> slots (2*l16, 2*l16+1); (p2,p3) -> +32.
        #pragma unroll
        for (int r = 0; r < 4; ++r) {
            const int row = quad * 4 + r;            // within wave's 16 rows
            const int f = f0 + wave * 16 + row;
            uint2 wb = *(const uint2*)&mbits[((size_t)b * F_DIM + f) * 64 + (t0 >> 5)];
            float p[4];
            #pragma unroll
            for (int ck = 0; ck < 4; ++ck) {
                unsigned wsel = (ck & 2) ? wb.y : wb.x;
                int bit = ((ck & 1) << 4) + l16;
                float pv = __builtin_amdgcn_exp2f(S[ck][r]);
                p[ck] = ((wsel >> bit) & 1u) ? pv : 0.f;
            }
            lsum[r] += (p[0] + p[1]) + (p[2] + p[3]);
            *(unsigned*)&Pw[row * LSTR + 2 * l16] = pk_bf16(p[0], p[1]);
            *(unsigned*)&Pw[row * LSTR + 32 + 2 * l16] = pk_bf16(p[2], p[3]);
        }

        // O += P . V  (both operands traverse slots in identical order)
        __builtin_amdgcn_s_setprio(1);
        #pragma unroll
        for (int ks = 0; ks < 2; ++ks) {
            bf16x8 pa = *(const bf16x8*)&Pw[l16 * LSTR + ks * 32 + quad * 8];
            #pragma unroll
            for (int ec = 0; ec < 4; ++ec) {
                bf16x8 vb = *(const bf16x8*)&Vt_lds[(ec * 16 + l16) * LSTR + ks * 32 + quad * 8];
                O[ec] = __builtin_amdgcn_mfma_f32_16x16x32_bf16(pa, vb, O[ec], 0, 0, 0);
            }
        }
        __builtin_amdgcn_s_setprio(0);
    }

    // epilogue: reduce l over the 16 lanes sharing each row, write ctx (bf16)
    #pragma unroll
    for (int r = 0; r < 4; ++r) {
        float l = lsum[r];
        #pragma unroll
        for (int d = 1; d < 16; d <<= 1) l += __shfl_xor(l, d);
        const int f = f0 + wave * 16 + quad * 4 + r;
        const float inv = 1.0f / l;
        #pragma unroll
        for (int ec = 0; ec < 4; ++ec) {
            ctxb[(size_t)(f * B_DIM + b) * H_DIM + n * 64 + ec * 16 + l16] = f2bf(O[ec][r] * inv);
        }
    }
}

// ---------------------------------------------------------------------------
extern "C" void kernel_launch(void* const* d_in, const int* in_sizes, int n_in,
                              void* d_out, int out_size, void* d_ws, size_t ws_size,
                              hipStream_t stream) {
    const float* q_input = (const float*)d_in[0];
    const void*  mask    = d_in[1];
    const float* w_qkv   = (const float*)d_in[2];
    const float* b_qkv   = (const float*)d_in[3];
    const float* w_out   = (const float*)d_in[4];
    const float* b_out   = (const float*)d_in[5];
    float* out = (float*)d_out;
    char* ws = (char*)d_ws;

    const size_t FUSED_WS = 42991616;   // through mbits

    if (ws_size >= FUSED_WS) {
        bf16*           qkv     = (bf16*)ws;                               // 25165824
        unsigned short* qin_bf  = (unsigned short*)(ws + 25165824);        // 8388608 (reused as ctx)
        unsigned short* ctx     = qin_bf;
        unsigned short* wqkv_bt = (unsigned short*)(ws + 33554432);        // 6291456
        unsigned short* wout_bt = (unsigned short*)(ws + 39845888);        // 2097152
        unsigned*       mbits   = (unsigned*)(ws + 41943040);              // 1048576

        prep_kernel<<<7172, 256, 0, stream>>>(q_input, mask, w_qkv, w_out, b_out,
                                              qin_bf, wqkv_bt, wout_bt, mbits,
                                              out + (size_t)M_DIM * H_DIM);
        gemm_bt_kernel<128, 128, true, true, true><<<dim3(24, 32), 256, 0, stream>>>(qin_bf, wqkv_bt, b_qkv, qkv, 3072);
        attn_mfma_kernel<<<dim3(16, 32), 512, 0, stream>>>(qkv, mbits, ctx);
        gemm_bt_kernel<64, 128, false, false, false><<<dim3(8, 64), 256, 0, stream>>>(ctx, wout_bt, nullptr, out, 1024);
    } else {
        // R9-proven fallback layout (peak ~40.9 MB), separate prep kernels
        bf16*           qkv     = (bf16*)ws;                               // 25165824
        unsigned short* qin_bf  = (unsigned short*)(ws + 25165824);        // 8388608 (reused as ctx)
        unsigned short* ctx     = qin_bf;
        unsigned short* wqkv_bt = (unsigned short*)(ws + 33554432);        // 6291456 (reused as wout_bt)
        unsigned short* wout_bt = wqkv_bt;
        unsigned*       mbits   = (unsigned*)(ws + 39845888);              // 1048576
        int*            flag    = (int*)(ws + 40894464);                   // 4

        detect_mask_kernel<<<1, 256, 0, stream>>>((const int*)mask, flag);
        pack_mask_kernel<<<1024, 256, 0, stream>>>((const int*)mask, (const unsigned char*)mask, flag, mbits);
        convert_kernel<<<2048, 256, 0, stream>>>(q_input, qin_bf);
        transpose_bf16_kernel<<<dim3(96, 32), 256, 0, stream>>>(w_qkv, wqkv_bt, 1024, 3072);
        gemm_bt_kernel<128, 128, true, true, true><<<dim3(24, 32), 256, 0, stream>>>(qin_bf, wqkv_bt, b_qkv, qkv, 3072);
        transpose_bf16_kernel<<<dim3(32, 32), 256, 0, stream>>>(w_out, wout_bt, 1024, 1024);
        attn_mfma_kernel<<<dim3(16, 32), 512, 0, stream>>>(qkv, mbits, ctx);
        gemm_bt_kernel<64, 128, false, false, false><<<dim3(8, 64), 256, 0, stream>>>(ctx, wout_bt, nullptr, out, 1024);
        bout_copy_kernel<<<4, 256, 0, stream>>>(b_out, out + (size_t)M_DIM * H_DIM);
    }
}

// Round 5
// 238.600 us; speedup vs baseline: 1.0111x; 1.0111x over previous
//
#include <hip/hip_runtime.h>
#include <hip/hip_bf16.h>
#include <math.h>

// Problem constants
#define F_DIM 2048
#define B_DIM 2
#define H_DIM 1024
#define N_HEADS 16
#define E_DIM 64
#define D3 3072          // 3*H
#define M_DIM 4096       // F*B

typedef __hip_bfloat16 bf16;
typedef __attribute__((ext_vector_type(8))) __bf16 bf16x8;
typedef __attribute__((ext_vector_type(8))) unsigned short u16x8;
typedef __attribute__((ext_vector_type(4))) float f32x4;

// float -> bf16 bits, round-to-nearest-even
static __device__ __forceinline__ unsigned short f2bf(float f) {
    unsigned u = __float_as_uint(f);
    return (unsigned short)((u + 0x7FFFu + ((u >> 16) & 1u)) >> 16);
}

// pack two floats to bf16x2 (RNE); HW packed convert when available
static __device__ __forceinline__ unsigned pk_bf16(float a, float b) {
#if __has_builtin(__builtin_amdgcn_cvt_pk_bf16_f32)
    typedef __attribute__((ext_vector_type(2))) __bf16 bf16x2;
    bf16x2 v = __builtin_amdgcn_cvt_pk_bf16_f32(a, b);
    unsigned u; __builtin_memcpy(&u, &v, 4); return u;
#else
    return (unsigned)f2bf(a) | ((unsigned)f2bf(b) << 16);
#endif
}

// async global->LDS, 16B per lane; lds ptr must be wave-uniform base
static __device__ __forceinline__ void glds16(const unsigned short* g, unsigned short* l) {
    __builtin_amdgcn_global_load_lds((const __attribute__((address_space(1))) unsigned int*)g,
                                     (__attribute__((address_space(3))) unsigned int*)l,
                                     16, 0, 0);
}

// 0.125 * log2(e): folded into q at QKV-gemm epilogue so softmax is exp2(S)
#define Q_SCALE 0.18033688011112042f

// ---------------------------------------------------------------------------
// Fused prep (R10-proven)
// ---------------------------------------------------------------------------
__global__ __launch_bounds__(256) void prep_kernel(const float* __restrict__ q_input,
                                                   const void* __restrict__ mask,
                                                   const float* __restrict__ w_qkv,
                                                   const float* __restrict__ w_out,
                                                   const float* __restrict__ b_out,
                                                   unsigned short* __restrict__ qin_bf,
                                                   unsigned short* __restrict__ wqkv_bt,
                                                   unsigned short* __restrict__ wout_bt,
                                                   unsigned* __restrict__ mbits,
                                                   float* __restrict__ bout_dst) {
    __shared__ float sh[32 * 33];
    const int bid = blockIdx.x;
    const int tid = threadIdx.x;

    if (bid < 2048) {                       // convert
        int i = (bid * 256 + tid) * 8;
        float4 a = *(const float4*)&q_input[i];
        float4 b = *(const float4*)&q_input[i + 4];
        u16x8 o;
        o[0] = f2bf(a.x); o[1] = f2bf(a.y); o[2] = f2bf(a.z); o[3] = f2bf(a.w);
        o[4] = f2bf(b.x); o[5] = f2bf(b.y); o[6] = f2bf(b.z); o[7] = f2bf(b.w);
        *(u16x8*)&qin_bf[i] = o;
    } else if (bid < 6144) {                // transposes
        const float* in; unsigned short* out; int R, C, bx, by;
        if (bid < 5120) { int idx = bid - 2048; in = w_qkv; out = wqkv_bt; R = 1024; C = 3072; bx = idx % 96; by = idx / 96; }
        else            { int idx = bid - 5120; in = w_out; out = wout_bt; R = 1024; C = 1024; bx = idx % 32; by = idx / 32; }
        float (*t)[33] = (float(*)[33])sh;
        const int c0 = bx * 32, r0 = by * 32;
        const int lc = tid & 31, lr = tid >> 5;
        #pragma unroll
        for (int i = 0; i < 4; ++i) {
            int r = lr + i * 8;
            t[r][lc] = in[(size_t)(r0 + r) * C + c0 + lc];
        }
        __syncthreads();
        #pragma unroll
        for (int i = 0; i < 4; ++i) {
            int r = lr + i * 8;
            out[(size_t)(c0 + r) * R + r0 + lc] = f2bf(t[lc][r]);
        }
    } else if (bid < 7168) {                // mask pack with inline detect
        int* shi = (int*)sh;
        int v = ((const int*)mask)[tid] & ~1;
        unsigned long long bal = __ballot(v != 0);
        if ((tid & 63) == 0) shi[tid >> 6] = (bal != 0) ? 1 : 0;
        __syncthreads();
        const int byte_mode = shi[0] | shi[1] | shi[2] | shi[3];
        int w = (bid - 6144) * 256 + tid;
        size_t base = (size_t)w * 32;
        unsigned out = 0;
        if (byte_mode) {
            const unsigned char* mu = (const unsigned char*)mask;
            #pragma unroll
            for (int j = 0; j < 32; ++j) out |= (mu[base + j] ? 1u : 0u) << j;
        } else {
            const int* mi = (const int*)mask;
            #pragma unroll
            for (int j = 0; j < 32; ++j) out |= (mi[base + j] ? 1u : 0u) << j;
        }
        mbits[w] = out;
    } else {                                // b_out copy
        int h = (bid - 7168) * 256 + tid;
        if (h < H_DIM) bout_dst[h] = b_out[h];
    }
}

// --------------------- fallback prep kernels (R9-proven) -------------------
__global__ void detect_mask_kernel(const int* __restrict__ mask_words, int* __restrict__ flag) {
    __shared__ int red[256];
    int v = mask_words[threadIdx.x];
    red[threadIdx.x] = v & ~1;
    __syncthreads();
    for (int s = 128; s > 0; s >>= 1) {
        if (threadIdx.x < s) red[threadIdx.x] |= red[threadIdx.x + s];
        __syncthreads();
    }
    if (threadIdx.x == 0) *flag = (red[0] != 0) ? 1 : 0;
}

__global__ void pack_mask_kernel(const int* __restrict__ mi, const unsigned char* __restrict__ mu,
                                 const int* __restrict__ flag, unsigned* __restrict__ bits) {
    int w = blockIdx.x * 256 + threadIdx.x;
    size_t base = (size_t)w * 32;
    unsigned out = 0;
    if (*flag) {
        #pragma unroll
        for (int j = 0; j < 32; ++j) out |= (mu[base + j] ? 1u : 0u) << j;
    } else {
        #pragma unroll
        for (int j = 0; j < 32; ++j) out |= (mi[base + j] ? 1u : 0u) << j;
    }
    bits[w] = out;
}

__global__ __launch_bounds__(256) void convert_kernel(const float* __restrict__ in,
                                                      unsigned short* __restrict__ out) {
    int i = (blockIdx.x * 256 + threadIdx.x) * 8;
    float4 a = *(const float4*)&in[i];
    float4 b = *(const float4*)&in[i + 4];
    u16x8 o;
    o[0] = f2bf(a.x); o[1] = f2bf(a.y); o[2] = f2bf(a.z); o[3] = f2bf(a.w);
    o[4] = f2bf(b.x); o[5] = f2bf(b.y); o[6] = f2bf(b.z); o[7] = f2bf(b.w);
    *(u16x8*)&out[i] = o;
}

__global__ __launch_bounds__(256) void transpose_bf16_kernel(const float* __restrict__ in,
                                                             unsigned short* __restrict__ out,
                                                             int R, int C) {
    __shared__ float t[32][33];
    const int c0 = blockIdx.x * 32, r0 = blockIdx.y * 32;
    const int lc = threadIdx.x & 31, lr = threadIdx.x >> 5;
    #pragma unroll
    for (int i = 0; i < 4; ++i) {
        int r = lr + i * 8;
        t[r][lc] = in[(size_t)(r0 + r) * C + c0 + lc];
    }
    __syncthreads();
    #pragma unroll
    for (int i = 0; i < 4; ++i) {
        int r = lr + i * 8;
        out[(size_t)(c0 + r) * R + r0 + lc] = f2bf(t[lc][r]);
    }
}

__global__ void bout_copy_kernel(const float* __restrict__ b_out, float* __restrict__ dst) {
    int h = blockIdx.x * 256 + threadIdx.x;
    if (h < H_DIM) dst[h] = b_out[h];
}

// ---------------------------------------------------------------------------
// m97-style bf16 MFMA GEMM, B-transposed input, tile BM x BN (mult of 64).
// SCALE_Q: multiply q-columns (col%192 < 64) by Q_SCALE in the epilogue
// (folds the attention 1/sqrt(E) and log2(e) into Q once).
// ---------------------------------------------------------------------------
template<int BM, int BN, bool ADD_BIAS, bool OUT_BF16, bool SCALE_Q>
__global__ __launch_bounds__(256) void gemm_bt_kernel(const unsigned short* __restrict__ A,
                                                      const unsigned short* __restrict__ Bt,
                                                      const float* __restrict__ bias,
                                                      void* __restrict__ Cout, int Nc) {
    __shared__ unsigned short Ald[BM * 32];
    __shared__ unsigned short Bld[BN * 32];
    constexpr int WM = BM / 2, WN = BN / 2;
    constexpr int MI = WM / 16, NI = WN / 16;
    constexpr int ACH = BM * 4;
    constexpr int TCH = (BM + BN) * 4;
    const int tid = threadIdx.x;
    const int wave = tid >> 6;
    const int lane = tid & 63;
    const int quad = lane >> 4;
    const int l16 = lane & 15;
    const int wm = (wave & 1) * WM;
    const int wn = (wave >> 1) * WN;
    const int m0 = blockIdx.y * BM;
    const int n0 = blockIdx.x * BN;

    f32x4 acc[MI][NI];
    #pragma unroll
    for (int i = 0; i < MI; ++i)
        #pragma unroll
        for (int j = 0; j < NI; ++j) acc[i][j] = (f32x4){0.f, 0.f, 0.f, 0.f};

    for (int k0 = 0; k0 < 1024; k0 += 32) {
        __syncthreads();
        #pragma unroll
        for (int rr = 0; rr < TCH / 256; ++rr) {
            const int chunk = rr * 256 + tid;
            const int wbase = (rr * 256 + wave * 64) * 8;
            if (chunk < ACH) {
                const int row = chunk >> 2, ko = (chunk & 3) * 8;
                glds16(&A[(size_t)(m0 + row) * 1024 + k0 + ko], &Ald[wbase]);
            } else {
                const int c2 = chunk - ACH;
                const int row = c2 >> 2, ko = (c2 & 3) * 8;
                glds16(&Bt[(size_t)(n0 + row) * 1024 + k0 + ko], &Bld[wbase - ACH * 8]);
            }
        }
        __syncthreads();

        bf16x8 af[MI], bfr[NI];
        #pragma unroll
        for (int i = 0; i < MI; ++i)
            af[i] = *(const bf16x8*)&Ald[(wm + i * 16 + l16) * 32 + quad * 8];
        #pragma unroll
        for (int j = 0; j < NI; ++j)
            bfr[j] = *(const bf16x8*)&Bld[(wn + j * 16 + l16) * 32 + quad * 8];
        #pragma unroll
        for (int mi = 0; mi < MI; ++mi)
            #pragma unroll
            for (int ni = 0; ni < NI; ++ni)
                acc[mi][ni] = __builtin_amdgcn_mfma_f32_16x16x32_bf16(af[mi], bfr[ni], acc[mi][ni], 0, 0, 0);
    }

    #pragma unroll
    for (int ni = 0; ni < NI; ++ni) {
        const int col = n0 + wn + ni * 16 + l16;
        const float bv = ADD_BIAS ? bias[col] : 0.f;
        const bool scale = SCALE_Q && ((col % 192) < 64);
        #pragma unroll
        for (int mi = 0; mi < MI; ++mi) {
            const int rowb = m0 + wm + mi * 16 + quad * 4;
            #pragma unroll
            for (int r = 0; r < 4; ++r) {
                float v = acc[mi][ni][r] + bv;
                if (SCALE_Q) v = scale ? v * Q_SCALE : v;
                if (OUT_BF16) ((unsigned short*)Cout)[(size_t)(rowb + r) * Nc + col] = f2bf(v);
                else          ((float*)Cout)[(size_t)(rowb + r) * Nc + col] = v;
            }
        }
    }
}

// ---------------------------------------------------------------------------
// MFMA flash attention. R13 change: grid is 512 blocks -> only 2 blocks/CU
// (16 waves/CU) is reachable, so cap occupancy at 4 waves/EU via
// __launch_bounds__(512, 4) -> VGPR budget 48 -> 128. Lets the compiler hoist
// the ~26 loop-invariant LDS fragment addresses + batch mask loads instead of
// recomputing every t0 iteration (R12 profile: VALUBusy 44% vs MfmaUtil 16%,
// VGPR_Count=48 = register-starved). Mask row base hoisted; 4 uint2 mask
// loads batched ahead of the exp2 arithmetic.
// ---------------------------------------------------------------------------
#define LSTR 72        // LDS row stride (elements) for K, Vt, and P
__global__ __launch_bounds__(512, 4) void attn_mfma_kernel(const bf16* __restrict__ qkv_,
                                                           const unsigned* __restrict__ mbits,
                                                           unsigned short* __restrict__ ctxb) {
    __shared__ unsigned short K_lds[64 * LSTR];        // [t][e]      9216 B
    __shared__ unsigned short Vt_lds[64 * LSTR];       // [e][slot]   9216 B
    __shared__ unsigned short P_lds[128 * LSTR];       // [row][slot] 18432 B

    const unsigned short* qkv = (const unsigned short*)qkv_;
    const int tid = threadIdx.x;
    const int wave = tid >> 6;          // 0..7
    const int lane = tid & 63;
    const int quad = lane >> 4;
    const int l16 = lane & 15;
    const int f0 = blockIdx.x * 128;
    const int b = blockIdx.y >> 4;
    const int n = blockIdx.y & 15;
    const int head = n * 192;

    // Q fragments [ks] (A layout): rows f0 + wave*16 + l16 (pre-scaled)
    bf16x8 qf[2];
    #pragma unroll
    for (int ks = 0; ks < 2; ++ks) {
        int f = f0 + wave * 16 + l16;
        qf[ks] = *(const bf16x8*)&qkv[(size_t)(f * B_DIM + b) * D3 + head + ks * 32 + quad * 8];
    }

    f32x4 O[4];
    #pragma unroll
    for (int ec = 0; ec < 4; ++ec) O[ec] = (f32x4){0.f, 0.f, 0.f, 0.f};
    float lsum[4] = {0.f, 0.f, 0.f, 0.f};

    unsigned short* Pw = P_lds + wave * 16 * LSTR;
    // loop-invariant mask row base: rows f0 + wave*16 + quad*4 + r, stride 64 words/row
    const unsigned* mrow = &mbits[((size_t)b * F_DIM + (f0 + wave * 16 + quad * 4)) * 64];

    for (int t0 = 0; t0 < F_DIM; t0 += 64) {
        __syncthreads();   // previous tile's LDS reads complete

        // stage K tile [64][64] row-major: 512 chunks, 1/thread
        {
            int tr = tid >> 3, e0 = (tid & 7) * 8;
            u16x8 kv = *(const u16x8*)&qkv[(size_t)((t0 + tr) * B_DIM + b) * D3 + head + 64 + e0];
            *(u16x8*)&K_lds[tr * LSTR + e0] = kv;
        }
        // stage V transposed with (t, t+16) interleave: slot h*32+2u(+o).
        if (tid < 256) {
            int u = tid & 15, h = (tid >> 4) & 1, e0 = (tid >> 5) * 8;
            int ta = t0 + h * 32 + u;
            u16x8 v0 = *(const u16x8*)&qkv[(size_t)(ta * B_DIM + b) * D3 + head + 128 + e0];
            u16x8 v1 = *(const u16x8*)&qkv[(size_t)((ta + 16) * B_DIM + b) * D3 + head + 128 + e0];
            #pragma unroll
            for (int j = 0; j < 8; ++j) {
                unsigned pk = (unsigned)v0[j] | ((unsigned)v1[j] << 16);
                *(unsigned*)&Vt_lds[(e0 + j) * LSTR + h * 32 + 2 * u] = pk;
            }
        }
        __syncthreads();   // staging visible

        // S = Q . K^T  [16 x 64] per wave; S[ck] covers t = ck*16 + l16
        f32x4 S[4];
        #pragma unroll
        for (int ck = 0; ck < 4; ++ck) S[ck] = (f32x4){0.f, 0.f, 0.f, 0.f};
        __builtin_amdgcn_s_setprio(1);
        #pragma unroll
        for (int ck = 0; ck < 4; ++ck) {
            bf16x8 kb0 = *(const bf16x8*)&K_lds[(ck * 16 + l16) * LSTR + quad * 8];
            bf16x8 kb1 = *(const bf16x8*)&K_lds[(ck * 16 + l16) * LSTR + 32 + quad * 8];
            S[ck] = __builtin_amdgcn_mfma_f32_16x16x32_bf16(qf[0], kb0, S[ck], 0, 0, 0);
            S[ck] = __builtin_amdgcn_mfma_f32_16x16x32_bf16(qf[1], kb1, S[ck], 0, 0, 0);
        }
        __builtin_amdgcn_s_setprio(0);

        // batch the 4 mask uint2 loads (overlap VMEM latency), then softmax.
        uint2 wbv[4];
        #pragma unroll
        for (int r = 0; r < 4; ++r)
            wbv[r] = *(const uint2*)&mrow[(size_t)r * 64 + (t0 >> 5)];

        // fixed-max softmax: p = mask ? exp2(S) : 0 (scale folded into Q);
        // packed P writes: (p0,p1) -> slots (2*l16, 2*l16+1); (p2,p3) -> +32.
        #pragma unroll
        for (int r = 0; r < 4; ++r) {
            const int row = quad * 4 + r;            // within wave's 16 rows
            float p[4];
            #pragma unroll
            for (int ck = 0; ck < 4; ++ck) {
                unsigned wsel = (ck & 2) ? wbv[r].y : wbv[r].x;
                int bit = ((ck & 1) << 4) + l16;
                float pv = __builtin_amdgcn_exp2f(S[ck][r]);
                p[ck] = ((wsel >> bit) & 1u) ? pv : 0.f;
            }
            lsum[r] += (p[0] + p[1]) + (p[2] + p[3]);
            *(unsigned*)&Pw[row * LSTR + 2 * l16] = pk_bf16(p[0], p[1]);
            *(unsigned*)&Pw[row * LSTR + 32 + 2 * l16] = pk_bf16(p[2], p[3]);
        }

        // O += P . V  (both operands traverse slots in identical order)
        __builtin_amdgcn_s_setprio(1);
        #pragma unroll
        for (int ks = 0; ks < 2; ++ks) {
            bf16x8 pa = *(const bf16x8*)&Pw[l16 * LSTR + ks * 32 + quad * 8];
            #pragma unroll
            for (int ec = 0; ec < 4; ++ec) {
                bf16x8 vb = *(const bf16x8*)&Vt_lds[(ec * 16 + l16) * LSTR + ks * 32 + quad * 8];
                O[ec] = __builtin_amdgcn_mfma_f32_16x16x32_bf16(pa, vb, O[ec], 0, 0, 0);
            }
        }
        __builtin_amdgcn_s_setprio(0);
    }

    // epilogue: reduce l over the 16 lanes sharing each row, write ctx (bf16)
    #pragma unroll
    for (int r = 0; r < 4; ++r) {
        float l = lsum[r];
        #pragma unroll
        for (int d = 1; d < 16; d <<= 1) l += __shfl_xor(l, d);
        const int f = f0 + wave * 16 + quad * 4 + r;
        const float inv = 1.0f / l;
        #pragma unroll
        for (int ec = 0; ec < 4; ++ec) {
            ctxb[(size_t)(f * B_DIM + b) * H_DIM + n * 64 + ec * 16 + l16] = f2bf(O[ec][r] * inv);
        }
    }
}

// ---------------------------------------------------------------------------
extern "C" void kernel_launch(void* const* d_in, const int* in_sizes, int n_in,
                              void* d_out, int out_size, void* d_ws, size_t ws_size,
                              hipStream_t stream) {
    const float* q_input = (const float*)d_in[0];
    const void*  mask    = d_in[1];
    const float* w_qkv   = (const float*)d_in[2];
    const float* b_qkv   = (const float*)d_in[3];
    const float* w_out   = (const float*)d_in[4];
    const float* b_out   = (const float*)d_in[5];
    float* out = (float*)d_out;
    char* ws = (char*)d_ws;

    const size_t FUSED_WS = 42991616;   // through mbits

    if (ws_size >= FUSED_WS) {
        bf16*           qkv     = (bf16*)ws;                               // 25165824
        unsigned short* qin_bf  = (unsigned short*)(ws + 25165824);        // 8388608 (reused as ctx)
        unsigned short* ctx     = qin_bf;
        unsigned short* wqkv_bt = (unsigned short*)(ws + 33554432);        // 6291456
        unsigned short* wout_bt = (unsigned short*)(ws + 39845888);        // 2097152
        unsigned*       mbits   = (unsigned*)(ws + 41943040);              // 1048576

        prep_kernel<<<7172, 256, 0, stream>>>(q_input, mask, w_qkv, w_out, b_out,
                                              qin_bf, wqkv_bt, wout_bt, mbits,
                                              out + (size_t)M_DIM * H_DIM);
        gemm_bt_kernel<128, 128, true, true, true><<<dim3(24, 32), 256, 0, stream>>>(qin_bf, wqkv_bt, b_qkv, qkv, 3072);
        attn_mfma_kernel<<<dim3(16, 32), 512, 0, stream>>>(qkv, mbits, ctx);
        gemm_bt_kernel<64, 128, false, false, false><<<dim3(8, 64), 256, 0, stream>>>(ctx, wout_bt, nullptr, out, 1024);
    } else {
        // R9-proven fallback layout (peak ~40.9 MB), separate prep kernels
        bf16*           qkv     = (bf16*)ws;                               // 25165824
        unsigned short* qin_bf  = (unsigned short*)(ws + 25165824);        // 8388608 (reused as ctx)
        unsigned short* ctx     = qin_bf;
        unsigned short* wqkv_bt = (unsigned short*)(ws + 33554432);        // 6291456 (reused as wout_bt)
        unsigned short* wout_bt = wqkv_bt;
        unsigned*       mbits   = (unsigned*)(ws + 39845888);              // 1048576
        int*            flag    = (int*)(ws + 40894464);                   // 4

        detect_mask_kernel<<<1, 256, 0, stream>>>((const int*)mask, flag);
        pack_mask_kernel<<<1024, 256, 0, stream>>>((const int*)mask, (const unsigned char*)mask, flag, mbits);
        convert_kernel<<<2048, 256, 0, stream>>>(q_input, qin_bf);
        transpose_bf16_kernel<<<dim3(96, 32), 256, 0, stream>>>(w_qkv, wqkv_bt, 1024, 3072);
        gemm_bt_kernel<128, 128, true, true, true><<<dim3(24, 32), 256, 0, stream>>>(qin_bf, wqkv_bt, b_qkv, qkv, 3072);
        transpose_bf16_kernel<<<dim3(32, 32), 256, 0, stream>>>(w_out, wout_bt, 1024, 1024);
        attn_mfma_kernel<<<dim3(16, 32), 512, 0, stream>>>(qkv, mbits, ctx);
        gemm_bt_kernel<64, 128, false, false, false><<<dim3(8, 64), 256, 0, stream>>>(ctx, wout_bt, nullptr, out, 1024);
        bout_copy_kernel<<<4, 256, 0, stream>>>(b_out, out + (size_t)M_DIM * H_DIM);
    }
}

// Round 6
// 236.061 us; speedup vs baseline: 1.0220x; 1.0108x over previous
//
#include <hip/hip_runtime.h>
#include <hip/hip_bf16.h>
#include <math.h>

// Problem constants
#define F_DIM 2048
#define B_DIM 2
#define H_DIM 1024
#define N_HEADS 16
#define E_DIM 64
#define D3 3072          // 3*H
#define M_DIM 4096       // F*B

typedef __hip_bfloat16 bf16;
typedef __attribute__((ext_vector_type(8))) __bf16 bf16x8;
typedef __attribute__((ext_vector_type(8))) unsigned short u16x8;
typedef __attribute__((ext_vector_type(4))) float f32x4;

// float -> bf16 bits, round-to-nearest-even
static __device__ __forceinline__ unsigned short f2bf(float f) {
    unsigned u = __float_as_uint(f);
    return (unsigned short)((u + 0x7FFFu + ((u >> 16) & 1u)) >> 16);
}

// pack two floats to bf16x2 (RNE); HW packed convert when available
static __device__ __forceinline__ unsigned pk_bf16(float a, float b) {
#if __has_builtin(__builtin_amdgcn_cvt_pk_bf16_f32)
    typedef __attribute__((ext_vector_type(2))) __bf16 bf16x2;
    bf16x2 v = __builtin_amdgcn_cvt_pk_bf16_f32(a, b);
    unsigned u; __builtin_memcpy(&u, &v, 4); return u;
#else
    return (unsigned)f2bf(a) | ((unsigned)f2bf(b) << 16);
#endif
}

// async global->LDS, 16B per lane; lds ptr must be wave-uniform base
static __device__ __forceinline__ void glds16(const unsigned short* g, unsigned short* l) {
    __builtin_amdgcn_global_load_lds((const __attribute__((address_space(1))) unsigned int*)g,
                                     (__attribute__((address_space(3))) unsigned int*)l,
                                     16, 0, 0);
}

// 0.125 * log2(e): folded into q at QKV-gemm epilogue so softmax is exp2(S)
#define Q_SCALE 0.18033688011112042f

// ---------------------------------------------------------------------------
// Fused prep (R10-proven)
// ---------------------------------------------------------------------------
__global__ __launch_bounds__(256) void prep_kernel(const float* __restrict__ q_input,
                                                   const void* __restrict__ mask,
                                                   const float* __restrict__ w_qkv,
                                                   const float* __restrict__ w_out,
                                                   const float* __restrict__ b_out,
                                                   unsigned short* __restrict__ qin_bf,
                                                   unsigned short* __restrict__ wqkv_bt,
                                                   unsigned short* __restrict__ wout_bt,
                                                   unsigned* __restrict__ mbits,
                                                   float* __restrict__ bout_dst) {
    __shared__ float sh[32 * 33];
    const int bid = blockIdx.x;
    const int tid = threadIdx.x;

    if (bid < 2048) {                       // convert
        int i = (bid * 256 + tid) * 8;
        float4 a = *(const float4*)&q_input[i];
        float4 b = *(const float4*)&q_input[i + 4];
        u16x8 o;
        o[0] = f2bf(a.x); o[1] = f2bf(a.y); o[2] = f2bf(a.z); o[3] = f2bf(a.w);
        o[4] = f2bf(b.x); o[5] = f2bf(b.y); o[6] = f2bf(b.z); o[7] = f2bf(b.w);
        *(u16x8*)&qin_bf[i] = o;
    } else if (bid < 6144) {                // transposes
        const float* in; unsigned short* out; int R, C, bx, by;
        if (bid < 5120) { int idx = bid - 2048; in = w_qkv; out = wqkv_bt; R = 1024; C = 3072; bx = idx % 96; by = idx / 96; }
        else            { int idx = bid - 5120; in = w_out; out = wout_bt; R = 1024; C = 1024; bx = idx % 32; by = idx / 32; }
        float (*t)[33] = (float(*)[33])sh;
        const int c0 = bx * 32, r0 = by * 32;
        const int lc = tid & 31, lr = tid >> 5;
        #pragma unroll
        for (int i = 0; i < 4; ++i) {
            int r = lr + i * 8;
            t[r][lc] = in[(size_t)(r0 + r) * C + c0 + lc];
        }
        __syncthreads();
        #pragma unroll
        for (int i = 0; i < 4; ++i) {
            int r = lr + i * 8;
            out[(size_t)(c0 + r) * R + r0 + lc] = f2bf(t[lc][r]);
        }
    } else if (bid < 7168) {                // mask pack with inline detect
        int* shi = (int*)sh;
        int v = ((const int*)mask)[tid] & ~1;
        unsigned long long bal = __ballot(v != 0);
        if ((tid & 63) == 0) shi[tid >> 6] = (bal != 0) ? 1 : 0;
        __syncthreads();
        const int byte_mode = shi[0] | shi[1] | shi[2] | shi[3];
        int w = (bid - 6144) * 256 + tid;
        size_t base = (size_t)w * 32;
        unsigned out = 0;
        if (byte_mode) {
            const unsigned char* mu = (const unsigned char*)mask;
            #pragma unroll
            for (int j = 0; j < 32; ++j) out |= (mu[base + j] ? 1u : 0u) << j;
        } else {
            const int* mi = (const int*)mask;
            #pragma unroll
            for (int j = 0; j < 32; ++j) out |= (mi[base + j] ? 1u : 0u) << j;
        }
        mbits[w] = out;
    } else {                                // b_out copy
        int h = (bid - 7168) * 256 + tid;
        if (h < H_DIM) bout_dst[h] = b_out[h];
    }
}

// --------------------- fallback prep kernels (R9-proven) -------------------
__global__ void detect_mask_kernel(const int* __restrict__ mask_words, int* __restrict__ flag) {
    __shared__ int red[256];
    int v = mask_words[threadIdx.x];
    red[threadIdx.x] = v & ~1;
    __syncthreads();
    for (int s = 128; s > 0; s >>= 1) {
        if (threadIdx.x < s) red[threadIdx.x] |= red[threadIdx.x + s];
        __syncthreads();
    }
    if (threadIdx.x == 0) *flag = (red[0] != 0) ? 1 : 0;
}

__global__ void pack_mask_kernel(const int* __restrict__ mi, const unsigned char* __restrict__ mu,
                                 const int* __restrict__ flag, unsigned* __restrict__ bits) {
    int w = blockIdx.x * 256 + threadIdx.x;
    size_t base = (size_t)w * 32;
    unsigned out = 0;
    if (*flag) {
        #pragma unroll
        for (int j = 0; j < 32; ++j) out |= (mu[base + j] ? 1u : 0u) << j;
    } else {
        #pragma unroll
        for (int j = 0; j < 32; ++j) out |= (mi[base + j] ? 1u : 0u) << j;
    }
    bits[w] = out;
}

__global__ __launch_bounds__(256) void convert_kernel(const float* __restrict__ in,
                                                      unsigned short* __restrict__ out) {
    int i = (blockIdx.x * 256 + threadIdx.x) * 8;
    float4 a = *(const float4*)&in[i];
    float4 b = *(const float4*)&in[i + 4];
    u16x8 o;
    o[0] = f2bf(a.x); o[1] = f2bf(a.y); o[2] = f2bf(a.z); o[3] = f2bf(a.w);
    o[4] = f2bf(b.x); o[5] = f2bf(b.y); o[6] = f2bf(b.z); o[7] = f2bf(b.w);
    *(u16x8*)&out[i] = o;
}

__global__ __launch_bounds__(256) void transpose_bf16_kernel(const float* __restrict__ in,
                                                             unsigned short* __restrict__ out,
                                                             int R, int C) {
    __shared__ float t[32][33];
    const int c0 = blockIdx.x * 32, r0 = blockIdx.y * 32;
    const int lc = threadIdx.x & 31, lr = threadIdx.x >> 5;
    #pragma unroll
    for (int i = 0; i < 4; ++i) {
        int r = lr + i * 8;
        t[r][lc] = in[(size_t)(r0 + r) * C + c0 + lc];
    }
    __syncthreads();
    #pragma unroll
    for (int i = 0; i < 4; ++i) {
        int r = lr + i * 8;
        out[(size_t)(c0 + r) * R + r0 + lc] = f2bf(t[lc][r]);
    }
}

__global__ void bout_copy_kernel(const float* __restrict__ b_out, float* __restrict__ dst) {
    int h = blockIdx.x * 256 + threadIdx.x;
    if (h < H_DIM) dst[h] = b_out[h];
}

// ---------------------------------------------------------------------------
// m97-style bf16 MFMA GEMM, B-transposed input, tile BM x BN (mult of 64).
// SCALE_Q: multiply q-columns (col%192 < 64) by Q_SCALE in the epilogue
// (folds the attention 1/sqrt(E) and log2(e) into Q once).
// ---------------------------------------------------------------------------
template<int BM, int BN, bool ADD_BIAS, bool OUT_BF16, bool SCALE_Q>
__global__ __launch_bounds__(256) void gemm_bt_kernel(const unsigned short* __restrict__ A,
                                                      const unsigned short* __restrict__ Bt,
                                                      const float* __restrict__ bias,
                                                      void* __restrict__ Cout, int Nc) {
    __shared__ unsigned short Ald[BM * 32];
    __shared__ unsigned short Bld[BN * 32];
    constexpr int WM = BM / 2, WN = BN / 2;
    constexpr int MI = WM / 16, NI = WN / 16;
    constexpr int ACH = BM * 4;
    constexpr int TCH = (BM + BN) * 4;
    const int tid = threadIdx.x;
    const int wave = tid >> 6;
    const int lane = tid & 63;
    const int quad = lane >> 4;
    const int l16 = lane & 15;
    const int wm = (wave & 1) * WM;
    const int wn = (wave >> 1) * WN;
    const int m0 = blockIdx.y * BM;
    const int n0 = blockIdx.x * BN;

    f32x4 acc[MI][NI];
    #pragma unroll
    for (int i = 0; i < MI; ++i)
        #pragma unroll
        for (int j = 0; j < NI; ++j) acc[i][j] = (f32x4){0.f, 0.f, 0.f, 0.f};

    for (int k0 = 0; k0 < 1024; k0 += 32) {
        __syncthreads();
        #pragma unroll
        for (int rr = 0; rr < TCH / 256; ++rr) {
            const int chunk = rr * 256 + tid;
            const int wbase = (rr * 256 + wave * 64) * 8;
            if (chunk < ACH) {
                const int row = chunk >> 2, ko = (chunk & 3) * 8;
                glds16(&A[(size_t)(m0 + row) * 1024 + k0 + ko], &Ald[wbase]);
            } else {
                const int c2 = chunk - ACH;
                const int row = c2 >> 2, ko = (c2 & 3) * 8;
                glds16(&Bt[(size_t)(n0 + row) * 1024 + k0 + ko], &Bld[wbase - ACH * 8]);
            }
        }
        __syncthreads();

        bf16x8 af[MI], bfr[NI];
        #pragma unroll
        for (int i = 0; i < MI; ++i)
            af[i] = *(const bf16x8*)&Ald[(wm + i * 16 + l16) * 32 + quad * 8];
        #pragma unroll
        for (int j = 0; j < NI; ++j)
            bfr[j] = *(const bf16x8*)&Bld[(wn + j * 16 + l16) * 32 + quad * 8];
        #pragma unroll
        for (int mi = 0; mi < MI; ++mi)
            #pragma unroll
            for (int ni = 0; ni < NI; ++ni)
                acc[mi][ni] = __builtin_amdgcn_mfma_f32_16x16x32_bf16(af[mi], bfr[ni], acc[mi][ni], 0, 0, 0);
    }

    #pragma unroll
    for (int ni = 0; ni < NI; ++ni) {
        const int col = n0 + wn + ni * 16 + l16;
        const float bv = ADD_BIAS ? bias[col] : 0.f;
        const bool scale = SCALE_Q && ((col % 192) < 64);
        #pragma unroll
        for (int mi = 0; mi < MI; ++mi) {
            const int rowb = m0 + wm + mi * 16 + quad * 4;
            #pragma unroll
            for (int r = 0; r < 4; ++r) {
                float v = acc[mi][ni][r] + bv;
                if (SCALE_Q) v = scale ? v * Q_SCALE : v;
                if (OUT_BF16) ((unsigned short*)Cout)[(size_t)(rowb + r) * Nc + col] = f2bf(v);
                else          ((float*)Cout)[(size_t)(rowb + r) * Nc + col] = v;
            }
        }
    }
}

// ---------------------------------------------------------------------------
// MFMA flash attention. R14: LSTR-72 padding replaced by linear 64-elem
// (128B) rows + XOR granule swizzle elem^=((row&7)<<3)  (byte^=(row&7)<<4).
// R13 profile: SQ_LDS_BANK_CONFLICT 9.44M cyc/dispatch = ~18% of CU-cycles.
// With stride-36-dword rows, lanes reading different rows at the same 16B
// col slot (K/Vt/P reads, K staging write) were 8-way conflicted. The
// swizzle spreads 8 consecutive rows' granules across all 8 bank groups:
// reads/writes drop to 2-way (free, m136). Same involution on EVERY access
// (G4 / rule21); no arithmetic change. LDS 36KB -> 32KB.
// ---------------------------------------------------------------------------
static __device__ __forceinline__ int swz(int row, int elem) {
    return row * 64 + (elem ^ ((row & 7) << 3));
}

__global__ __launch_bounds__(512, 4) void attn_mfma_kernel(const bf16* __restrict__ qkv_,
                                                           const unsigned* __restrict__ mbits,
                                                           unsigned short* __restrict__ ctxb) {
    __shared__ unsigned short K_lds[64 * 64];          // [t][e]      8192 B
    __shared__ unsigned short Vt_lds[64 * 64];         // [e][slot]   8192 B
    __shared__ unsigned short P_lds[128 * 64];         // [row][slot] 16384 B

    const unsigned short* qkv = (const unsigned short*)qkv_;
    const int tid = threadIdx.x;
    const int wave = tid >> 6;          // 0..7
    const int lane = tid & 63;
    const int quad = lane >> 4;
    const int l16 = lane & 15;
    const int f0 = blockIdx.x * 128;
    const int b = blockIdx.y >> 4;
    const int n = blockIdx.y & 15;
    const int head = n * 192;

    // Q fragments [ks] (A layout): rows f0 + wave*16 + l16 (pre-scaled)
    bf16x8 qf[2];
    #pragma unroll
    for (int ks = 0; ks < 2; ++ks) {
        int f = f0 + wave * 16 + l16;
        qf[ks] = *(const bf16x8*)&qkv[(size_t)(f * B_DIM + b) * D3 + head + ks * 32 + quad * 8];
    }

    f32x4 O[4];
    #pragma unroll
    for (int ec = 0; ec < 4; ++ec) O[ec] = (f32x4){0.f, 0.f, 0.f, 0.f};
    float lsum[4] = {0.f, 0.f, 0.f, 0.f};

    unsigned short* Pw = P_lds + wave * 16 * 64;
    // loop-invariant mask row base: rows f0 + wave*16 + quad*4 + r, stride 64 words/row
    const unsigned* mrow = &mbits[((size_t)b * F_DIM + (f0 + wave * 16 + quad * 4)) * 64];

    for (int t0 = 0; t0 < F_DIM; t0 += 64) {
        __syncthreads();   // previous tile's LDS reads complete

        // stage K tile [64][64] row-major (swizzled): 512 chunks, 1/thread
        {
            int tr = tid >> 3, e0s = tid & 7;          // row, 16B-slot
            u16x8 kv = *(const u16x8*)&qkv[(size_t)((t0 + tr) * B_DIM + b) * D3 + head + 64 + e0s * 8];
            *(u16x8*)&K_lds[swz(tr, e0s * 8)] = kv;
        }
        // stage V transposed with (t, t+16) interleave: slot h*32+2u(+o), swizzled.
        if (tid < 256) {
            int u = tid & 15, h = (tid >> 4) & 1, e0 = (tid >> 5) * 8;
            int ta = t0 + h * 32 + u;
            u16x8 v0 = *(const u16x8*)&qkv[(size_t)(ta * B_DIM + b) * D3 + head + 128 + e0];
            u16x8 v1 = *(const u16x8*)&qkv[(size_t)((ta + 16) * B_DIM + b) * D3 + head + 128 + e0];
            #pragma unroll
            for (int j = 0; j < 8; ++j) {
                unsigned pk = (unsigned)v0[j] | ((unsigned)v1[j] << 16);
                *(unsigned*)&Vt_lds[swz(e0 + j, h * 32 + 2 * u)] = pk;
            }
        }
        __syncthreads();   // staging visible

        // S = Q . K^T  [16 x 64] per wave; S[ck] covers t = ck*16 + l16
        f32x4 S[4];
        #pragma unroll
        for (int ck = 0; ck < 4; ++ck) S[ck] = (f32x4){0.f, 0.f, 0.f, 0.f};
        __builtin_amdgcn_s_setprio(1);
        #pragma unroll
        for (int ck = 0; ck < 4; ++ck) {
            bf16x8 kb0 = *(const bf16x8*)&K_lds[swz(ck * 16 + l16, quad * 8)];
            bf16x8 kb1 = *(const bf16x8*)&K_lds[swz(ck * 16 + l16, 32 + quad * 8)];
            S[ck] = __builtin_amdgcn_mfma_f32_16x16x32_bf16(qf[0], kb0, S[ck], 0, 0, 0);
            S[ck] = __builtin_amdgcn_mfma_f32_16x16x32_bf16(qf[1], kb1, S[ck], 0, 0, 0);
        }
        __builtin_amdgcn_s_setprio(0);

        // batch the 4 mask uint2 loads (overlap VMEM latency), then softmax.
        uint2 wbv[4];
        #pragma unroll
        for (int r = 0; r < 4; ++r)
            wbv[r] = *(const uint2*)&mrow[(size_t)r * 64 + (t0 >> 5)];

        // fixed-max softmax: p = mask ? exp2(S) : 0 (scale folded into Q);
        // packed P writes: (p0,p1) -> slots (2*l16, 2*l16+1); (p2,p3) -> +32.
        #pragma unroll
        for (int r = 0; r < 4; ++r) {
            const int row = quad * 4 + r;            // within wave's 16 rows
            float p[4];
            #pragma unroll
            for (int ck = 0; ck < 4; ++ck) {
                unsigned wsel = (ck & 2) ? wbv[r].y : wbv[r].x;
                int bit = ((ck & 1) << 4) + l16;
                float pv = __builtin_amdgcn_exp2f(S[ck][r]);
                p[ck] = ((wsel >> bit) & 1u) ? pv : 0.f;
            }
            lsum[r] += (p[0] + p[1]) + (p[2] + p[3]);
            *(unsigned*)&Pw[swz(row, 2 * l16)] = pk_bf16(p[0], p[1]);
            *(unsigned*)&Pw[swz(row, 32 + 2 * l16)] = pk_bf16(p[2], p[3]);
        }

        // O += P . V  (both operands traverse slots in identical order)
        __builtin_amdgcn_s_setprio(1);
        #pragma unroll
        for (int ks = 0; ks < 2; ++ks) {
            bf16x8 pa = *(const bf16x8*)&Pw[swz(l16, ks * 32 + quad * 8)];
            #pragma unroll
            for (int ec = 0; ec < 4; ++ec) {
                bf16x8 vb = *(const bf16x8*)&Vt_lds[swz(ec * 16 + l16, ks * 32 + quad * 8)];
                O[ec] = __builtin_amdgcn_mfma_f32_16x16x32_bf16(pa, vb, O[ec], 0, 0, 0);
            }
        }
        __builtin_amdgcn_s_setprio(0);
    }

    // epilogue: reduce l over the 16 lanes sharing each row, write ctx (bf16)
    #pragma unroll
    for (int r = 0; r < 4; ++r) {
        float l = lsum[r];
        #pragma unroll
        for (int d = 1; d < 16; d <<= 1) l += __shfl_xor(l, d);
        const int f = f0 + wave * 16 + quad * 4 + r;
        const float inv = 1.0f / l;
        #pragma unroll
        for (int ec = 0; ec < 4; ++ec) {
            ctxb[(size_t)(f * B_DIM + b) * H_DIM + n * 64 + ec * 16 + l16] = f2bf(O[ec][r] * inv);
        }
    }
}

// ---------------------------------------------------------------------------
extern "C" void kernel_launch(void* const* d_in, const int* in_sizes, int n_in,
                              void* d_out, int out_size, void* d_ws, size_t ws_size,
                              hipStream_t stream) {
    const float* q_input = (const float*)d_in[0];
    const void*  mask    = d_in[1];
    const float* w_qkv   = (const float*)d_in[2];
    const float* b_qkv   = (const float*)d_in[3];
    const float* w_out   = (const float*)d_in[4];
    const float* b_out   = (const float*)d_in[5];
    float* out = (float*)d_out;
    char* ws = (char*)d_ws;

    const size_t FUSED_WS = 42991616;   // through mbits

    if (ws_size >= FUSED_WS) {
        bf16*           qkv     = (bf16*)ws;                               // 25165824
        unsigned short* qin_bf  = (unsigned short*)(ws + 25165824);        // 8388608 (reused as ctx)
        unsigned short* ctx     = qin_bf;
        unsigned short* wqkv_bt = (unsigned short*)(ws + 33554432);        // 6291456
        unsigned short* wout_bt = (unsigned short*)(ws + 39845888);        // 2097152
        unsigned*       mbits   = (unsigned*)(ws + 41943040);              // 1048576

        prep_kernel<<<7172, 256, 0, stream>>>(q_input, mask, w_qkv, w_out, b_out,
                                              qin_bf, wqkv_bt, wout_bt, mbits,
                                              out + (size_t)M_DIM * H_DIM);
        gemm_bt_kernel<128, 128, true, true, true><<<dim3(24, 32), 256, 0, stream>>>(qin_bf, wqkv_bt, b_qkv, qkv, 3072);
        attn_mfma_kernel<<<dim3(16, 32), 512, 0, stream>>>(qkv, mbits, ctx);
        gemm_bt_kernel<64, 128, false, false, false><<<dim3(8, 64), 256, 0, stream>>>(ctx, wout_bt, nullptr, out, 1024);
    } else {
        // R9-proven fallback layout (peak ~40.9 MB), separate prep kernels
        bf16*           qkv     = (bf16*)ws;                               // 25165824
        unsigned short* qin_bf  = (unsigned short*)(ws + 25165824);        // 8388608 (reused as ctx)
        unsigned short* ctx     = qin_bf;
        unsigned short* wqkv_bt = (unsigned short*)(ws + 33554432);        // 6291456 (reused as wout_bt)
        unsigned short* wout_bt = wqkv_bt;
        unsigned*       mbits   = (unsigned*)(ws + 39845888);              // 1048576
        int*            flag    = (int*)(ws + 40894464);                   // 4

        detect_mask_kernel<<<1, 256, 0, stream>>>((const int*)mask, flag);
        pack_mask_kernel<<<1024, 256, 0, stream>>>((const int*)mask, (const unsigned char*)mask, flag, mbits);
        convert_kernel<<<2048, 256, 0, stream>>>(q_input, qin_bf);
        transpose_bf16_kernel<<<dim3(96, 32), 256, 0, stream>>>(w_qkv, wqkv_bt, 1024, 3072);
        gemm_bt_kernel<128, 128, true, true, true><<<dim3(24, 32), 256, 0, stream>>>(qin_bf, wqkv_bt, b_qkv, qkv, 3072);
        transpose_bf16_kernel<<<dim3(32, 32), 256, 0, stream>>>(w_out, wout_bt, 1024, 1024);
        attn_mfma_kernel<<<dim3(16, 32), 512, 0, stream>>>(qkv, mbits, ctx);
        gemm_bt_kernel<64, 128, false, false, false><<<dim3(8, 64), 256, 0, stream>>>(ctx, wout_bt, nullptr, out, 1024);
        bout_copy_kernel<<<4, 256, 0, stream>>>(b_out, out + (size_t)M_DIM * H_DIM);
    }
}

// Round 7
// 233.139 us; speedup vs baseline: 1.0348x; 1.0125x over previous
//
#include <hip/hip_runtime.h>
#include <hip/hip_bf16.h>
#include <math.h>

// Problem constants
#define F_DIM 2048
#define B_DIM 2
#define H_DIM 1024
#define N_HEADS 16
#define E_DIM 64
#define D3 3072          // 3*H
#define M_DIM 4096       // F*B

typedef __hip_bfloat16 bf16;
typedef __attribute__((ext_vector_type(8))) __bf16 bf16x8;
typedef __attribute__((ext_vector_type(8))) unsigned short u16x8;
typedef __attribute__((ext_vector_type(4))) float f32x4;

// float -> bf16 bits, round-to-nearest-even
static __device__ __forceinline__ unsigned short f2bf(float f) {
    unsigned u = __float_as_uint(f);
    return (unsigned short)((u + 0x7FFFu + ((u >> 16) & 1u)) >> 16);
}

// pack two floats to bf16x2 (RNE); HW packed convert when available
static __device__ __forceinline__ unsigned pk_bf16(float a, float b) {
#if __has_builtin(__builtin_amdgcn_cvt_pk_bf16_f32)
    typedef __attribute__((ext_vector_type(2))) __bf16 bf16x2;
    bf16x2 v = __builtin_amdgcn_cvt_pk_bf16_f32(a, b);
    unsigned u; __builtin_memcpy(&u, &v, 4); return u;
#else
    return (unsigned)f2bf(a) | ((unsigned)f2bf(b) << 16);
#endif
}

// async global->LDS, 16B per lane; lds ptr must be wave-uniform base
static __device__ __forceinline__ void glds16(const unsigned short* g, unsigned short* l) {
    __builtin_amdgcn_global_load_lds((const __attribute__((address_space(1))) unsigned int*)g,
                                     (__attribute__((address_space(3))) unsigned int*)l,
                                     16, 0, 0);
}

// 0.125 * log2(e): folded into q at QKV-gemm epilogue so softmax is exp2(S)
#define Q_SCALE 0.18033688011112042f

// ---------------------------------------------------------------------------
// Fused prep (R10-proven)
// ---------------------------------------------------------------------------
__global__ __launch_bounds__(256) void prep_kernel(const float* __restrict__ q_input,
                                                   const void* __restrict__ mask,
                                                   const float* __restrict__ w_qkv,
                                                   const float* __restrict__ w_out,
                                                   const float* __restrict__ b_out,
                                                   unsigned short* __restrict__ qin_bf,
                                                   unsigned short* __restrict__ wqkv_bt,
                                                   unsigned short* __restrict__ wout_bt,
                                                   unsigned* __restrict__ mbits,
                                                   float* __restrict__ bout_dst) {
    __shared__ float sh[32 * 33];
    const int bid = blockIdx.x;
    const int tid = threadIdx.x;

    if (bid < 2048) {                       // convert
        int i = (bid * 256 + tid) * 8;
        float4 a = *(const float4*)&q_input[i];
        float4 b = *(const float4*)&q_input[i + 4];
        u16x8 o;
        o[0] = f2bf(a.x); o[1] = f2bf(a.y); o[2] = f2bf(a.z); o[3] = f2bf(a.w);
        o[4] = f2bf(b.x); o[5] = f2bf(b.y); o[6] = f2bf(b.z); o[7] = f2bf(b.w);
        *(u16x8*)&qin_bf[i] = o;
    } else if (bid < 6144) {                // transposes
        const float* in; unsigned short* out; int R, C, bx, by;
        if (bid < 5120) { int idx = bid - 2048; in = w_qkv; out = wqkv_bt; R = 1024; C = 3072; bx = idx % 96; by = idx / 96; }
        else            { int idx = bid - 5120; in = w_out; out = wout_bt; R = 1024; C = 1024; bx = idx % 32; by = idx / 32; }
        float (*t)[33] = (float(*)[33])sh;
        const int c0 = bx * 32, r0 = by * 32;
        const int lc = tid & 31, lr = tid >> 5;
        #pragma unroll
        for (int i = 0; i < 4; ++i) {
            int r = lr + i * 8;
            t[r][lc] = in[(size_t)(r0 + r) * C + c0 + lc];
        }
        __syncthreads();
        #pragma unroll
        for (int i = 0; i < 4; ++i) {
            int r = lr + i * 8;
            out[(size_t)(c0 + r) * R + r0 + lc] = f2bf(t[lc][r]);
        }
    } else if (bid < 7168) {                // mask pack with inline detect
        int* shi = (int*)sh;
        int v = ((const int*)mask)[tid] & ~1;
        unsigned long long bal = __ballot(v != 0);
        if ((tid & 63) == 0) shi[tid >> 6] = (bal != 0) ? 1 : 0;
        __syncthreads();
        const int byte_mode = shi[0] | shi[1] | shi[2] | shi[3];
        int w = (bid - 6144) * 256 + tid;
        size_t base = (size_t)w * 32;
        unsigned out = 0;
        if (byte_mode) {
            const unsigned char* mu = (const unsigned char*)mask;
            #pragma unroll
            for (int j = 0; j < 32; ++j) out |= (mu[base + j] ? 1u : 0u) << j;
        } else {
            const int* mi = (const int*)mask;
            #pragma unroll
            for (int j = 0; j < 32; ++j) out |= (mi[base + j] ? 1u : 0u) << j;
        }
        mbits[w] = out;
    } else {                                // b_out copy
        int h = (bid - 7168) * 256 + tid;
        if (h < H_DIM) bout_dst[h] = b_out[h];
    }
}

// --------------------- fallback prep kernels (R9-proven) -------------------
__global__ void detect_mask_kernel(const int* __restrict__ mask_words, int* __restrict__ flag) {
    __shared__ int red[256];
    int v = mask_words[threadIdx.x];
    red[threadIdx.x] = v & ~1;
    __syncthreads();
    for (int s = 128; s > 0; s >>= 1) {
        if (threadIdx.x < s) red[threadIdx.x] |= red[threadIdx.x + s];
        __syncthreads();
    }
    if (threadIdx.x == 0) *flag = (red[0] != 0) ? 1 : 0;
}

__global__ void pack_mask_kernel(const int* __restrict__ mi, const unsigned char* __restrict__ mu,
                                 const int* __restrict__ flag, unsigned* __restrict__ bits) {
    int w = blockIdx.x * 256 + threadIdx.x;
    size_t base = (size_t)w * 32;
    unsigned out = 0;
    if (*flag) {
        #pragma unroll
        for (int j = 0; j < 32; ++j) out |= (mu[base + j] ? 1u : 0u) << j;
    } else {
        #pragma unroll
        for (int j = 0; j < 32; ++j) out |= (mi[base + j] ? 1u : 0u) << j;
    }
    bits[w] = out;
}

__global__ __launch_bounds__(256) void convert_kernel(const float* __restrict__ in,
                                                      unsigned short* __restrict__ out) {
    int i = (blockIdx.x * 256 + threadIdx.x) * 8;
    float4 a = *(const float4*)&in[i];
    float4 b = *(const float4*)&in[i + 4];
    u16x8 o;
    o[0] = f2bf(a.x); o[1] = f2bf(a.y); o[2] = f2bf(a.z); o[3] = f2bf(a.w);
    o[4] = f2bf(b.x); o[5] = f2bf(b.y); o[6] = f2bf(b.z); o[7] = f2bf(b.w);
    *(u16x8*)&out[i] = o;
}

__global__ __launch_bounds__(256) void transpose_bf16_kernel(const float* __restrict__ in,
                                                             unsigned short* __restrict__ out,
                                                             int R, int C) {
    __shared__ float t[32][33];
    const int c0 = blockIdx.x * 32, r0 = blockIdx.y * 32;
    const int lc = threadIdx.x & 31, lr = threadIdx.x >> 5;
    #pragma unroll
    for (int i = 0; i < 4; ++i) {
        int r = lr + i * 8;
        t[r][lc] = in[(size_t)(r0 + r) * C + c0 + lc];
    }
    __syncthreads();
    #pragma unroll
    for (int i = 0; i < 4; ++i) {
        int r = lr + i * 8;
        out[(size_t)(c0 + r) * R + r0 + lc] = f2bf(t[lc][r]);
    }
}

__global__ void bout_copy_kernel(const float* __restrict__ b_out, float* __restrict__ dst) {
    int h = blockIdx.x * 256 + threadIdx.x;
    if (h < H_DIM) dst[h] = b_out[h];
}

// ---------------------------------------------------------------------------
// m97-style bf16 MFMA GEMM, B-transposed input, tile BM x BN (mult of 64).
// SCALE_Q: multiply q-columns (col%192 < 64) by Q_SCALE in the epilogue
// (folds the attention 1/sqrt(E) and log2(e) into Q once).
// ---------------------------------------------------------------------------
template<int BM, int BN, bool ADD_BIAS, bool OUT_BF16, bool SCALE_Q>
__global__ __launch_bounds__(256) void gemm_bt_kernel(const unsigned short* __restrict__ A,
                                                      const unsigned short* __restrict__ Bt,
                                                      const float* __restrict__ bias,
                                                      void* __restrict__ Cout, int Nc) {
    __shared__ unsigned short Ald[BM * 32];
    __shared__ unsigned short Bld[BN * 32];
    constexpr int WM = BM / 2, WN = BN / 2;
    constexpr int MI = WM / 16, NI = WN / 16;
    constexpr int ACH = BM * 4;
    constexpr int TCH = (BM + BN) * 4;
    const int tid = threadIdx.x;
    const int wave = tid >> 6;
    const int lane = tid & 63;
    const int quad = lane >> 4;
    const int l16 = lane & 15;
    const int wm = (wave & 1) * WM;
    const int wn = (wave >> 1) * WN;
    const int m0 = blockIdx.y * BM;
    const int n0 = blockIdx.x * BN;

    f32x4 acc[MI][NI];
    #pragma unroll
    for (int i = 0; i < MI; ++i)
        #pragma unroll
        for (int j = 0; j < NI; ++j) acc[i][j] = (f32x4){0.f, 0.f, 0.f, 0.f};

    for (int k0 = 0; k0 < 1024; k0 += 32) {
        __syncthreads();
        #pragma unroll
        for (int rr = 0; rr < TCH / 256; ++rr) {
            const int chunk = rr * 256 + tid;
            const int wbase = (rr * 256 + wave * 64) * 8;
            if (chunk < ACH) {
                const int row = chunk >> 2, ko = (chunk & 3) * 8;
                glds16(&A[(size_t)(m0 + row) * 1024 + k0 + ko], &Ald[wbase]);
            } else {
                const int c2 = chunk - ACH;
                const int row = c2 >> 2, ko = (c2 & 3) * 8;
                glds16(&Bt[(size_t)(n0 + row) * 1024 + k0 + ko], &Bld[wbase - ACH * 8]);
            }
        }
        __syncthreads();

        bf16x8 af[MI], bfr[NI];
        #pragma unroll
        for (int i = 0; i < MI; ++i)
            af[i] = *(const bf16x8*)&Ald[(wm + i * 16 + l16) * 32 + quad * 8];
        #pragma unroll
        for (int j = 0; j < NI; ++j)
            bfr[j] = *(const bf16x8*)&Bld[(wn + j * 16 + l16) * 32 + quad * 8];
        #pragma unroll
        for (int mi = 0; mi < MI; ++mi)
            #pragma unroll
            for (int ni = 0; ni < NI; ++ni)
                acc[mi][ni] = __builtin_amdgcn_mfma_f32_16x16x32_bf16(af[mi], bfr[ni], acc[mi][ni], 0, 0, 0);
    }

    #pragma unroll
    for (int ni = 0; ni < NI; ++ni) {
        const int col = n0 + wn + ni * 16 + l16;
        const float bv = ADD_BIAS ? bias[col] : 0.f;
        const bool scale = SCALE_Q && ((col % 192) < 64);
        #pragma unroll
        for (int mi = 0; mi < MI; ++mi) {
            const int rowb = m0 + wm + mi * 16 + quad * 4;
            #pragma unroll
            for (int r = 0; r < 4; ++r) {
                float v = acc[mi][ni][r] + bv;
                if (SCALE_Q) v = scale ? v * Q_SCALE : v;
                if (OUT_BF16) ((unsigned short*)Cout)[(size_t)(rowb + r) * Nc + col] = f2bf(v);
                else          ((float*)Cout)[(size_t)(rowb + r) * Nc + col] = v;
            }
        }
    }
}

// ---------------------------------------------------------------------------
// MFMA flash attention. R15: T14 async-STAGE split. R14 profile: bank
// conflicts 9.44M -> 0 but dur flat => conflicts were hidden; critical path
// is barrier -> global-load latency -> ds_write -> barrier -> compute.
// Now the K/V global loads for tile t+1 are issued into REGISTERS right
// after barrier B of tile t, so L2 latency (~200-500cy) hides under tile
// t's MFMA+softmax. ds_write stays in the same barrier-protected window
// (no sync change, no race surface; m214 v27: +17%). +12 VGPR.
// R14 XOR swizzle retained: elem^=((row&7)<<3), same involution on every
// access; conflicts stay 0.
// ---------------------------------------------------------------------------
static __device__ __forceinline__ int swz(int row, int elem) {
    return row * 64 + (elem ^ ((row & 7) << 3));
}

__global__ __launch_bounds__(512, 4) void attn_mfma_kernel(const bf16* __restrict__ qkv_,
                                                           const unsigned* __restrict__ mbits,
                                                           unsigned short* __restrict__ ctxb) {
    __shared__ unsigned short K_lds[64 * 64];          // [t][e]      8192 B
    __shared__ unsigned short Vt_lds[64 * 64];         // [e][slot]   8192 B
    __shared__ unsigned short P_lds[128 * 64];         // [row][slot] 16384 B

    const unsigned short* qkv = (const unsigned short*)qkv_;
    const int tid = threadIdx.x;
    const int wave = tid >> 6;          // 0..7
    const int lane = tid & 63;
    const int quad = lane >> 4;
    const int l16 = lane & 15;
    const int f0 = blockIdx.x * 128;
    const int b = blockIdx.y >> 4;
    const int n = blockIdx.y & 15;
    const int head = n * 192;

    // Q fragments [ks] (A layout): rows f0 + wave*16 + l16 (pre-scaled)
    bf16x8 qf[2];
    #pragma unroll
    for (int ks = 0; ks < 2; ++ks) {
        int f = f0 + wave * 16 + l16;
        qf[ks] = *(const bf16x8*)&qkv[(size_t)(f * B_DIM + b) * D3 + head + ks * 32 + quad * 8];
    }

    f32x4 O[4];
    #pragma unroll
    for (int ec = 0; ec < 4; ++ec) O[ec] = (f32x4){0.f, 0.f, 0.f, 0.f};
    float lsum[4] = {0.f, 0.f, 0.f, 0.f};

    unsigned short* Pw = P_lds + wave * 16 * 64;
    // loop-invariant mask row base: rows f0 + wave*16 + quad*4 + r, stride 64 words/row
    const unsigned* mrow = &mbits[((size_t)b * F_DIM + (f0 + wave * 16 + quad * 4)) * 64];

    // ---- staging-address invariants ----
    const int ktr = tid >> 3, ke0 = (tid & 7) * 8;      // K: row, elem base
    const int vu = tid & 15, vh = (tid >> 4) & 1, ve0 = (tid >> 5) * 8;  // V (tid<256)
    // K row base: qkv[((t + ktr)*B + b)*D3 + head + 64 + ke0]
    const unsigned short* kbase = &qkv[(size_t)((size_t)ktr * B_DIM + b) * D3 + head + 64 + ke0];
    // V rows: ta = t + vh*32 + vu (and +16)
    const unsigned short* vbase0 = &qkv[(size_t)((size_t)(vh * 32 + vu) * B_DIM + b) * D3 + head + 128 + ve0];
    const unsigned short* vbase1 = vbase0 + (size_t)16 * B_DIM * D3;
    const size_t tstride = (size_t)B_DIM * D3;          // per-t-row elements

    // ---- prefetch registers ----
    u16x8 kreg, vreg0, vreg1;

    // prologue: issue loads for tile 0
    kreg = *(const u16x8*)&kbase[0];
    if (tid < 256) {
        vreg0 = *(const u16x8*)&vbase0[0];
        vreg1 = *(const u16x8*)&vbase1[0];
    }

    for (int t0 = 0; t0 < F_DIM; t0 += 64) {
        __syncthreads();   // A: previous tile's LDS reads complete

        // write staged registers to LDS (swizzled)
        *(u16x8*)&K_lds[swz(ktr, ke0)] = kreg;
        if (tid < 256) {
            #pragma unroll
            for (int j = 0; j < 8; ++j) {
                unsigned pk = (unsigned)vreg0[j] | ((unsigned)vreg1[j] << 16);
                *(unsigned*)&Vt_lds[swz(ve0 + j, vh * 32 + 2 * vu)] = pk;
            }
        }
        __syncthreads();   // B: staging visible

        // issue next tile's loads now -> latency hides under compute below
        {
            int tn = (t0 + 64 < F_DIM) ? (t0 + 64) : t0;   // clamp (values unused last iter)
            kreg = *(const u16x8*)&kbase[(size_t)tn * tstride];
            if (tid < 256) {
                vreg0 = *(const u16x8*)&vbase0[(size_t)tn * tstride];
                vreg1 = *(const u16x8*)&vbase1[(size_t)tn * tstride];
            }
        }

        // S = Q . K^T  [16 x 64] per wave; S[ck] covers t = ck*16 + l16
        f32x4 S[4];
        #pragma unroll
        for (int ck = 0; ck < 4; ++ck) S[ck] = (f32x4){0.f, 0.f, 0.f, 0.f};
        __builtin_amdgcn_s_setprio(1);
        #pragma unroll
        for (int ck = 0; ck < 4; ++ck) {
            bf16x8 kb0 = *(const bf16x8*)&K_lds[swz(ck * 16 + l16, quad * 8)];
            bf16x8 kb1 = *(const bf16x8*)&K_lds[swz(ck * 16 + l16, 32 + quad * 8)];
            S[ck] = __builtin_amdgcn_mfma_f32_16x16x32_bf16(qf[0], kb0, S[ck], 0, 0, 0);
            S[ck] = __builtin_amdgcn_mfma_f32_16x16x32_bf16(qf[1], kb1, S[ck], 0, 0, 0);
        }
        __builtin_amdgcn_s_setprio(0);

        // batch the 4 mask uint2 loads, then softmax.
        uint2 wbv[4];
        #pragma unroll
        for (int r = 0; r < 4; ++r)
            wbv[r] = *(const uint2*)&mrow[(size_t)r * 64 + (t0 >> 5)];

        // fixed-max softmax: p = mask ? exp2(S) : 0 (scale folded into Q);
        // packed P writes: (p0,p1) -> slots (2*l16, 2*l16+1); (p2,p3) -> +32.
        #pragma unroll
        for (int r = 0; r < 4; ++r) {
            const int row = quad * 4 + r;            // within wave's 16 rows
            float p[4];
            #pragma unroll
            for (int ck = 0; ck < 4; ++ck) {
                unsigned wsel = (ck & 2) ? wbv[r].y : wbv[r].x;
                int bit = ((ck & 1) << 4) + l16;
                float pv = __builtin_amdgcn_exp2f(S[ck][r]);
                p[ck] = ((wsel >> bit) & 1u) ? pv : 0.f;
            }
            lsum[r] += (p[0] + p[1]) + (p[2] + p[3]);
            *(unsigned*)&Pw[swz(row, 2 * l16)] = pk_bf16(p[0], p[1]);
            *(unsigned*)&Pw[swz(row, 32 + 2 * l16)] = pk_bf16(p[2], p[3]);
        }

        // O += P . V  (both operands traverse slots in identical order)
        __builtin_amdgcn_s_setprio(1);
        #pragma unroll
        for (int ks = 0; ks < 2; ++ks) {
            bf16x8 pa = *(const bf16x8*)&Pw[swz(l16, ks * 32 + quad * 8)];
            #pragma unroll
            for (int ec = 0; ec < 4; ++ec) {
                bf16x8 vb = *(const bf16x8*)&Vt_lds[swz(ec * 16 + l16, ks * 32 + quad * 8)];
                O[ec] = __builtin_amdgcn_mfma_f32_16x16x32_bf16(pa, vb, O[ec], 0, 0, 0);
            }
        }
        __builtin_amdgcn_s_setprio(0);
    }

    // epilogue: reduce l over the 16 lanes sharing each row, write ctx (bf16)
    #pragma unroll
    for (int r = 0; r < 4; ++r) {
        float l = lsum[r];
        #pragma unroll
        for (int d = 1; d < 16; d <<= 1) l += __shfl_xor(l, d);
        const int f = f0 + wave * 16 + quad * 4 + r;
        const float inv = 1.0f / l;
        #pragma unroll
        for (int ec = 0; ec < 4; ++ec) {
            ctxb[(size_t)(f * B_DIM + b) * H_DIM + n * 64 + ec * 16 + l16] = f2bf(O[ec][r] * inv);
        }
    }
}

// ---------------------------------------------------------------------------
extern "C" void kernel_launch(void* const* d_in, const int* in_sizes, int n_in,
                              void* d_out, int out_size, void* d_ws, size_t ws_size,
                              hipStream_t stream) {
    const float* q_input = (const float*)d_in[0];
    const void*  mask    = d_in[1];
    const float* w_qkv   = (const float*)d_in[2];
    const float* b_qkv   = (const float*)d_in[3];
    const float* w_out   = (const float*)d_in[4];
    const float* b_out   = (const float*)d_in[5];
    float* out = (float*)d_out;
    char* ws = (char*)d_ws;

    const size_t FUSED_WS = 42991616;   // through mbits

    if (ws_size >= FUSED_WS) {
        bf16*           qkv     = (bf16*)ws;                               // 25165824
        unsigned short* qin_bf  = (unsigned short*)(ws + 25165824);        // 8388608 (reused as ctx)
        unsigned short* ctx     = qin_bf;
        unsigned short* wqkv_bt = (unsigned short*)(ws + 33554432);        // 6291456
        unsigned short* wout_bt = (unsigned short*)(ws + 39845888);        // 2097152
        unsigned*       mbits   = (unsigned*)(ws + 41943040);              // 1048576

        prep_kernel<<<7172, 256, 0, stream>>>(q_input, mask, w_qkv, w_out, b_out,
                                              qin_bf, wqkv_bt, wout_bt, mbits,
                                              out + (size_t)M_DIM * H_DIM);
        gemm_bt_kernel<128, 128, true, true, true><<<dim3(24, 32), 256, 0, stream>>>(qin_bf, wqkv_bt, b_qkv, qkv, 3072);
        attn_mfma_kernel<<<dim3(16, 32), 512, 0, stream>>>(qkv, mbits, ctx);
        gemm_bt_kernel<64, 128, false, false, false><<<dim3(8, 64), 256, 0, stream>>>(ctx, wout_bt, nullptr, out, 1024);
    } else {
        // R9-proven fallback layout (peak ~40.9 MB), separate prep kernels
        bf16*           qkv     = (bf16*)ws;                               // 25165824
        unsigned short* qin_bf  = (unsigned short*)(ws + 25165824);        // 8388608 (reused as ctx)
        unsigned short* ctx     = qin_bf;
        unsigned short* wqkv_bt = (unsigned short*)(ws + 33554432);        // 6291456 (reused as wout_bt)
        unsigned short* wout_bt = wqkv_bt;
        unsigned*       mbits   = (unsigned*)(ws + 39845888);              // 1048576
        int*            flag    = (int*)(ws + 40894464);                   // 4

        detect_mask_kernel<<<1, 256, 0, stream>>>((const int*)mask, flag);
        pack_mask_kernel<<<1024, 256, 0, stream>>>((const int*)mask, (const unsigned char*)mask, flag, mbits);
        convert_kernel<<<2048, 256, 0, stream>>>(q_input, qin_bf);
        transpose_bf16_kernel<<<dim3(96, 32), 256, 0, stream>>>(w_qkv, wqkv_bt, 1024, 3072);
        gemm_bt_kernel<128, 128, true, true, true><<<dim3(24, 32), 256, 0, stream>>>(qin_bf, wqkv_bt, b_qkv, qkv, 3072);
        transpose_bf16_kernel<<<dim3(32, 32), 256, 0, stream>>>(w_out, wout_bt, 1024, 1024);
        attn_mfma_kernel<<<dim3(16, 32), 512, 0, stream>>>(qkv, mbits, ctx);
        gemm_bt_kernel<64, 128, false, false, false><<<dim3(8, 64), 256, 0, stream>>>(ctx, wout_bt, nullptr, out, 1024);
        bout_copy_kernel<<<4, 256, 0, stream>>>(b_out, out + (size_t)M_DIM * H_DIM);
    }
}

// Round 10
// 232.594 us; speedup vs baseline: 1.0372x; 1.0023x over previous
//
#include <hip/hip_runtime.h>
#include <hip/hip_bf16.h>
#include <math.h>

// Problem constants
#define F_DIM 2048
#define B_DIM 2
#define H_DIM 1024
#define N_HEADS 16
#define E_DIM 64
#define D3 3072          // 3*H
#define M_DIM 4096       // F*B

typedef __hip_bfloat16 bf16;
typedef __attribute__((ext_vector_type(8))) __bf16 bf16x8;
typedef __attribute__((ext_vector_type(8))) unsigned short u16x8;
typedef __attribute__((ext_vector_type(4))) float f32x4;

// float -> bf16 bits, round-to-nearest-even
static __device__ __forceinline__ unsigned short f2bf(float f) {
    unsigned u = __float_as_uint(f);
    return (unsigned short)((u + 0x7FFFu + ((u >> 16) & 1u)) >> 16);
}

// pack two floats to bf16x2 (RNE); HW packed convert when available
static __device__ __forceinline__ unsigned pk_bf16(float a, float b) {
#if __has_builtin(__builtin_amdgcn_cvt_pk_bf16_f32)
    typedef __attribute__((ext_vector_type(2))) __bf16 bf16x2;
    bf16x2 v = __builtin_amdgcn_cvt_pk_bf16_f32(a, b);
    unsigned u; __builtin_memcpy(&u, &v, 4); return u;
#else
    return (unsigned)f2bf(a) | ((unsigned)f2bf(b) << 16);
#endif
}

// async global->LDS, 16B per lane; lds ptr must be wave-uniform base
static __device__ __forceinline__ void glds16(const unsigned short* g, unsigned short* l) {
    __builtin_amdgcn_global_load_lds((const __attribute__((address_space(1))) unsigned int*)g,
                                     (__attribute__((address_space(3))) unsigned int*)l,
                                     16, 0, 0);
}

// 0.125 * log2(e): folded into q at QKV-gemm epilogue so softmax is exp2(S)
#define Q_SCALE 0.18033688011112042f

// ---------------------------------------------------------------------------
// Fused prep (R10-proven)
// ---------------------------------------------------------------------------
__global__ __launch_bounds__(256) void prep_kernel(const float* __restrict__ q_input,
                                                   const void* __restrict__ mask,
                                                   const float* __restrict__ w_qkv,
                                                   const float* __restrict__ w_out,
                                                   const float* __restrict__ b_out,
                                                   unsigned short* __restrict__ qin_bf,
                                                   unsigned short* __restrict__ wqkv_bt,
                                                   unsigned short* __restrict__ wout_bt,
                                                   unsigned* __restrict__ mbits,
                                                   float* __restrict__ bout_dst) {
    __shared__ float sh[32 * 33];
    const int bid = blockIdx.x;
    const int tid = threadIdx.x;

    if (bid < 2048) {                       // convert
        int i = (bid * 256 + tid) * 8;
        float4 a = *(const float4*)&q_input[i];
        float4 b = *(const float4*)&q_input[i + 4];
        u16x8 o;
        o[0] = f2bf(a.x); o[1] = f2bf(a.y); o[2] = f2bf(a.z); o[3] = f2bf(a.w);
        o[4] = f2bf(b.x); o[5] = f2bf(b.y); o[6] = f2bf(b.z); o[7] = f2bf(b.w);
        *(u16x8*)&qin_bf[i] = o;
    } else if (bid < 6144) {                // transposes
        const float* in; unsigned short* out; int R, C, bx, by;
        if (bid < 5120) { int idx = bid - 2048; in = w_qkv; out = wqkv_bt; R = 1024; C = 3072; bx = idx % 96; by = idx / 96; }
        else            { int idx = bid - 5120; in = w_out; out = wout_bt; R = 1024; C = 1024; bx = idx % 32; by = idx / 32; }
        float (*t)[33] = (float(*)[33])sh;
        const int c0 = bx * 32, r0 = by * 32;
        const int lc = tid & 31, lr = tid >> 5;
        #pragma unroll
        for (int i = 0; i < 4; ++i) {
            int r = lr + i * 8;
            t[r][lc] = in[(size_t)(r0 + r) * C + c0 + lc];
        }
        __syncthreads();
        #pragma unroll
        for (int i = 0; i < 4; ++i) {
            int r = lr + i * 8;
            out[(size_t)(c0 + r) * R + r0 + lc] = f2bf(t[lc][r]);
        }
    } else if (bid < 7168) {                // mask pack with inline detect
        int* shi = (int*)sh;
        int v = ((const int*)mask)[tid] & ~1;
        unsigned long long bal = __ballot(v != 0);
        if ((tid & 63) == 0) shi[tid >> 6] = (bal != 0) ? 1 : 0;
        __syncthreads();
        const int byte_mode = shi[0] | shi[1] | shi[2] | shi[3];
        int w = (bid - 6144) * 256 + tid;
        size_t base = (size_t)w * 32;
        unsigned out = 0;
        if (byte_mode) {
            const unsigned char* mu = (const unsigned char*)mask;
            #pragma unroll
            for (int j = 0; j < 32; ++j) out |= (mu[base + j] ? 1u : 0u) << j;
        } else {
            const int* mi = (const int*)mask;
            #pragma unroll
            for (int j = 0; j < 32; ++j) out |= (mi[base + j] ? 1u : 0u) << j;
        }
        mbits[w] = out;
    } else {                                // b_out copy
        int h = (bid - 7168) * 256 + tid;
        if (h < H_DIM) bout_dst[h] = b_out[h];
    }
}

// --------------------- fallback prep kernels (R9-proven) -------------------
__global__ void detect_mask_kernel(const int* __restrict__ mask_words, int* __restrict__ flag) {
    __shared__ int red[256];
    int v = mask_words[threadIdx.x];
    red[threadIdx.x] = v & ~1;
    __syncthreads();
    for (int s = 128; s > 0; s >>= 1) {
        if (threadIdx.x < s) red[threadIdx.x] |= red[threadIdx.x + s];
        __syncthreads();
    }
    if (threadIdx.x == 0) *flag = (red[0] != 0) ? 1 : 0;
}

__global__ void pack_mask_kernel(const int* __restrict__ mi, const unsigned char* __restrict__ mu,
                                 const int* __restrict__ flag, unsigned* __restrict__ bits) {
    int w = blockIdx.x * 256 + threadIdx.x;
    size_t base = (size_t)w * 32;
    unsigned out = 0;
    if (*flag) {
        #pragma unroll
        for (int j = 0; j < 32; ++j) out |= (mu[base + j] ? 1u : 0u) << j;
    } else {
        #pragma unroll
        for (int j = 0; j < 32; ++j) out |= (mi[base + j] ? 1u : 0u) << j;
    }
    bits[w] = out;
}

__global__ __launch_bounds__(256) void convert_kernel(const float* __restrict__ in,
                                                      unsigned short* __restrict__ out) {
    int i = (blockIdx.x * 256 + threadIdx.x) * 8;
    float4 a = *(const float4*)&in[i];
    float4 b = *(const float4*)&in[i + 4];
    u16x8 o;
    o[0] = f2bf(a.x); o[1] = f2bf(a.y); o[2] = f2bf(a.z); o[3] = f2bf(a.w);
    o[4] = f2bf(b.x); o[5] = f2bf(b.y); o[6] = f2bf(b.z); o[7] = f2bf(b.w);
    *(u16x8*)&out[i] = o;
}

__global__ __launch_bounds__(256) void transpose_bf16_kernel(const float* __restrict__ in,
                                                             unsigned short* __restrict__ out,
                                                             int R, int C) {
    __shared__ float t[32][33];
    const int c0 = blockIdx.x * 32, r0 = blockIdx.y * 32;
    const int lc = threadIdx.x & 31, lr = threadIdx.x >> 5;
    #pragma unroll
    for (int i = 0; i < 4; ++i) {
        int r = lr + i * 8;
        t[r][lc] = in[(size_t)(r0 + r) * C + c0 + lc];
    }
    __syncthreads();
    #pragma unroll
    for (int i = 0; i < 4; ++i) {
        int r = lr + i * 8;
        out[(size_t)(c0 + r) * R + r0 + lc] = f2bf(t[lc][r]);
    }
}

__global__ void bout_copy_kernel(const float* __restrict__ b_out, float* __restrict__ dst) {
    int h = blockIdx.x * 256 + threadIdx.x;
    if (h < H_DIM) dst[h] = b_out[h];
}

// ---------------------------------------------------------------------------
// m97-style bf16 MFMA GEMM, B-transposed input, tile BM x BN (mult of 64).
// SCALE_Q: multiply q-columns (col%192 < 64) by Q_SCALE in the epilogue
// (folds the attention 1/sqrt(E) and log2(e) into Q once).
// ---------------------------------------------------------------------------
template<int BM, int BN, bool ADD_BIAS, bool OUT_BF16, bool SCALE_Q>
__global__ __launch_bounds__(256) void gemm_bt_kernel(const unsigned short* __restrict__ A,
                                                      const unsigned short* __restrict__ Bt,
                                                      const float* __restrict__ bias,
                                                      void* __restrict__ Cout, int Nc) {
    __shared__ unsigned short Ald[BM * 32];
    __shared__ unsigned short Bld[BN * 32];
    constexpr int WM = BM / 2, WN = BN / 2;
    constexpr int MI = WM / 16, NI = WN / 16;
    constexpr int ACH = BM * 4;
    constexpr int TCH = (BM + BN) * 4;
    const int tid = threadIdx.x;
    const int wave = tid >> 6;
    const int lane = tid & 63;
    const int quad = lane >> 4;
    const int l16 = lane & 15;
    const int wm = (wave & 1) * WM;
    const int wn = (wave >> 1) * WN;
    const int m0 = blockIdx.y * BM;
    const int n0 = blockIdx.x * BN;

    f32x4 acc[MI][NI];
    #pragma unroll
    for (int i = 0; i < MI; ++i)
        #pragma unroll
        for (int j = 0; j < NI; ++j) acc[i][j] = (f32x4){0.f, 0.f, 0.f, 0.f};

    for (int k0 = 0; k0 < 1024; k0 += 32) {
        __syncthreads();
        #pragma unroll
        for (int rr = 0; rr < TCH / 256; ++rr) {
            const int chunk = rr * 256 + tid;
            const int wbase = (rr * 256 + wave * 64) * 8;
            if (chunk < ACH) {
                const int row = chunk >> 2, ko = (chunk & 3) * 8;
                glds16(&A[(size_t)(m0 + row) * 1024 + k0 + ko], &Ald[wbase]);
            } else {
                const int c2 = chunk - ACH;
                const int row = c2 >> 2, ko = (c2 & 3) * 8;
                glds16(&Bt[(size_t)(n0 + row) * 1024 + k0 + ko], &Bld[wbase - ACH * 8]);
            }
        }
        __syncthreads();

        bf16x8 af[MI], bfr[NI];
        #pragma unroll
        for (int i = 0; i < MI; ++i)
            af[i] = *(const bf16x8*)&Ald[(wm + i * 16 + l16) * 32 + quad * 8];
        #pragma unroll
        for (int j = 0; j < NI; ++j)
            bfr[j] = *(const bf16x8*)&Bld[(wn + j * 16 + l16) * 32 + quad * 8];
        #pragma unroll
        for (int mi = 0; mi < MI; ++mi)
            #pragma unroll
            for (int ni = 0; ni < NI; ++ni)
                acc[mi][ni] = __builtin_amdgcn_mfma_f32_16x16x32_bf16(af[mi], bfr[ni], acc[mi][ni], 0, 0, 0);
    }

    #pragma unroll
    for (int ni = 0; ni < NI; ++ni) {
        const int col = n0 + wn + ni * 16 + l16;
        const float bv = ADD_BIAS ? bias[col] : 0.f;
        const bool scale = SCALE_Q && ((col % 192) < 64);
        #pragma unroll
        for (int mi = 0; mi < MI; ++mi) {
            const int rowb = m0 + wm + mi * 16 + quad * 4;
            #pragma unroll
            for (int r = 0; r < 4; ++r) {
                float v = acc[mi][ni][r] + bv;
                if (SCALE_Q) v = scale ? v * Q_SCALE : v;
                if (OUT_BF16) ((unsigned short*)Cout)[(size_t)(rowb + r) * Nc + col] = f2bf(v);
                else          ((float*)Cout)[(size_t)(rowb + r) * Nc + col] = v;
            }
        }
    }
}

// ---------------------------------------------------------------------------
// MFMA flash attention. R16: K/V LDS ping-pong double-buffer -> ONE
// __syncthreads per t0-iteration (was 2). Rationale: R15 profile shows
// MfmaUtil 18 + VALUBusy 47 => ~35% both-idle; conflicts 0, loads
// prefetched (T14), HBM 12% -> the barrier drains are the remaining stall.
// P_lds is wave-private (each wave writes/reads only its own 16 rows) so it
// needs no barrier; the 2 barriers only protected K/V. Race matrix for the
// single-barrier ping-pong: iter i writes buf[p], barrier, reads buf[p];
// wave skew is bounded by one barrier, so any wave writing buf[p^1] at iter
// i+1 can only coexist with waves computing iter i from buf[p] (disjoint),
// and all reads of buf[p^1] (iter i-1) drained at iter i's barrier. LDS
// 32->48 KB (still 2 blocks/CU, grid-capped). T14 prefetch + R14 swizzle
// retained (same involution, conflicts stay 0).
// ---------------------------------------------------------------------------
static __device__ __forceinline__ int swz(int row, int elem) {
    return row * 64 + (elem ^ ((row & 7) << 3));
}

__global__ __launch_bounds__(512, 4) void attn_mfma_kernel(const bf16* __restrict__ qkv_,
                                                           const unsigned* __restrict__ mbits,
                                                           unsigned short* __restrict__ ctxb) {
    __shared__ unsigned short K_lds[2][64 * 64];       // [buf][t][e]      2x8192 B
    __shared__ unsigned short Vt_lds[2][64 * 64];      // [buf][e][slot]   2x8192 B
    __shared__ unsigned short P_lds[128 * 64];         // [row][slot]      16384 B

    const unsigned short* qkv = (const unsigned short*)qkv_;
    const int tid = threadIdx.x;
    const int wave = tid >> 6;          // 0..7
    const int lane = tid & 63;
    const int quad = lane >> 4;
    const int l16 = lane & 15;
    const int f0 = blockIdx.x * 128;
    const int b = blockIdx.y >> 4;
    const int n = blockIdx.y & 15;
    const int head = n * 192;

    // Q fragments [ks] (A layout): rows f0 + wave*16 + l16 (pre-scaled)
    bf16x8 qf[2];
    #pragma unroll
    for (int ks = 0; ks < 2; ++ks) {
        int f = f0 + wave * 16 + l16;
        qf[ks] = *(const bf16x8*)&qkv[(size_t)(f * B_DIM + b) * D3 + head + ks * 32 + quad * 8];
    }

    f32x4 O[4];
    #pragma unroll
    for (int ec = 0; ec < 4; ++ec) O[ec] = (f32x4){0.f, 0.f, 0.f, 0.f};
    float lsum[4] = {0.f, 0.f, 0.f, 0.f};

    unsigned short* Pw = P_lds + wave * 16 * 64;
    // loop-invariant mask row base: rows f0 + wave*16 + quad*4 + r, stride 64 words/row
    const unsigned* mrow = &mbits[((size_t)b * F_DIM + (f0 + wave * 16 + quad * 4)) * 64];

    // ---- staging-address invariants ----
    const int ktr = tid >> 3, ke0 = (tid & 7) * 8;      // K: row, elem base
    const int vu = tid & 15, vh = (tid >> 4) & 1, ve0 = (tid >> 5) * 8;  // V (tid<256)
    const unsigned short* kbase = &qkv[(size_t)((size_t)ktr * B_DIM + b) * D3 + head + 64 + ke0];
    const unsigned short* vbase0 = &qkv[(size_t)((size_t)(vh * 32 + vu) * B_DIM + b) * D3 + head + 128 + ve0];
    const unsigned short* vbase1 = vbase0 + (size_t)16 * B_DIM * D3;
    const size_t tstride = (size_t)B_DIM * D3;          // per-t-row elements

    // ---- prefetch registers ----
    u16x8 kreg, vreg0, vreg1;

    // prologue: issue loads for tile 0
    kreg = *(const u16x8*)&kbase[0];
    if (tid < 256) {
        vreg0 = *(const u16x8*)&vbase0[0];
        vreg1 = *(const u16x8*)&vbase1[0];
    }

    int p = 0;
    for (int t0 = 0; t0 < F_DIM; t0 += 64) {
        // write staged registers to LDS buf[p] (swizzled); no barrier needed
        // before: buf[p]'s prior readers drained at the previous iteration's
        // barrier (see race matrix in header comment).
        *(u16x8*)&K_lds[p][swz(ktr, ke0)] = kreg;
        if (tid < 256) {
            #pragma unroll
            for (int j = 0; j < 8; ++j) {
                unsigned pk = (unsigned)vreg0[j] | ((unsigned)vreg1[j] << 16);
                *(unsigned*)&Vt_lds[p][swz(ve0 + j, vh * 32 + 2 * vu)] = pk;
            }
        }
        __syncthreads();   // staging visible; prev iteration's reads drained

        // issue next tile's loads now -> latency hides under compute below
        {
            int tn = (t0 + 64 < F_DIM) ? (t0 + 64) : t0;   // clamp (values unused last iter)
            kreg = *(const u16x8*)&kbase[(size_t)tn * tstride];
            if (tid < 256) {
                vreg0 = *(const u16x8*)&vbase0[(size_t)tn * tstride];
                vreg1 = *(const u16x8*)&vbase1[(size_t)tn * tstride];
            }
        }

        // S = Q . K^T  [16 x 64] per wave; S[ck] covers t = ck*16 + l16
        f32x4 S[4];
        #pragma unroll
        for (int ck = 0; ck < 4; ++ck) S[ck] = (f32x4){0.f, 0.f, 0.f, 0.f};
        __builtin_amdgcn_s_setprio(1);
        #pragma unroll
        for (int ck = 0; ck < 4; ++ck) {
            bf16x8 kb0 = *(const bf16x8*)&K_lds[p][swz(ck * 16 + l16, quad * 8)];
            bf16x8 kb1 = *(const bf16x8*)&K_lds[p][swz(ck * 16 + l16, 32 + quad * 8)];
            S[ck] = __builtin_amdgcn_mfma_f32_16x16x32_bf16(qf[0], kb0, S[ck], 0, 0, 0);
            S[ck] = __builtin_amdgcn_mfma_f32_16x16x32_bf16(qf[1], kb1, S[ck], 0, 0, 0);
        }
        __builtin_amdgcn_s_setprio(0);

        // batch the 4 mask uint2 loads, then softmax.
        uint2 wbv[4];
        #pragma unroll
        for (int r = 0; r < 4; ++r)
            wbv[r] = *(const uint2*)&mrow[(size_t)r * 64 + (t0 >> 5)];

        // fixed-max softmax: p = mask ? exp2(S) : 0 (scale folded into Q);
        // packed P writes: (p0,p1) -> slots (2*l16, 2*l16+1); (p2,p3) -> +32.
        #pragma unroll
        for (int r = 0; r < 4; ++r) {
            const int row = quad * 4 + r;            // within wave's 16 rows
            float pv4[4];
            #pragma unroll
            for (int ck = 0; ck < 4; ++ck) {
                unsigned wsel = (ck & 2) ? wbv[r].y : wbv[r].x;
                int bit = ((ck & 1) << 4) + l16;
                float pv = __builtin_amdgcn_exp2f(S[ck][r]);
                pv4[ck] = ((wsel >> bit) & 1u) ? pv : 0.f;
            }
            lsum[r] += (pv4[0] + pv4[1]) + (pv4[2] + pv4[3]);
            *(unsigned*)&Pw[swz(row, 2 * l16)] = pk_bf16(pv4[0], pv4[1]);
            *(unsigned*)&Pw[swz(row, 32 + 2 * l16)] = pk_bf16(pv4[2], pv4[3]);
        }

        // O += P . V  (both operands traverse slots in identical order).
        // P is wave-private: lgkmcnt ordering within the wave suffices.
        __builtin_amdgcn_s_setprio(1);
        #pragma unroll
        for (int ks = 0; ks < 2; ++ks) {
            bf16x8 pa = *(const bf16x8*)&Pw[swz(l16, ks * 32 + quad * 8)];
            #pragma unroll
            for (int ec = 0; ec < 4; ++ec) {
                bf16x8 vb = *(const bf16x8*)&Vt_lds[p][swz(ec * 16 + l16, ks * 32 + quad * 8)];
                O[ec] = __builtin_amdgcn_mfma_f32_16x16x32_bf16(pa, vb, O[ec], 0, 0, 0);
            }
        }
        __builtin_amdgcn_s_setprio(0);

        p ^= 1;
    }

    // epilogue: reduce l over the 16 lanes sharing each row, write ctx (bf16)
    #pragma unroll
    for (int r = 0; r < 4; ++r) {
        float l = lsum[r];
        #pragma unroll
        for (int d = 1; d < 16; d <<= 1) l += __shfl_xor(l, d);
        const int f = f0 + wave * 16 + quad * 4 + r;
        const float inv = 1.0f / l;
        #pragma unroll
        for (int ec = 0; ec < 4; ++ec) {
            ctxb[(size_t)(f * B_DIM + b) * H_DIM + n * 64 + ec * 16 + l16] = f2bf(O[ec][r] * inv);
        }
    }
}

// ---------------------------------------------------------------------------
extern "C" void kernel_launch(void* const* d_in, const int* in_sizes, int n_in,
                              void* d_out, int out_size, void* d_ws, size_t ws_size,
                              hipStream_t stream) {
    const float* q_input = (const float*)d_in[0];
    const void*  mask    = d_in[1];
    const float* w_qkv   = (const float*)d_in[2];
    const float* b_qkv   = (const float*)d_in[3];
    const float* w_out   = (const float*)d_in[4];
    const float* b_out   = (const float*)d_in[5];
    float* out = (float*)d_out;
    char* ws = (char*)d_ws;

    const size_t FUSED_WS = 42991616;   // through mbits

    if (ws_size >= FUSED_WS) {
        bf16*           qkv     = (bf16*)ws;                               // 25165824
        unsigned short* qin_bf  = (unsigned short*)(ws + 25165824);        // 8388608 (reused as ctx)
        unsigned short* ctx     = qin_bf;
        unsigned short* wqkv_bt = (unsigned short*)(ws + 33554432);        // 6291456
        unsigned short* wout_bt = (unsigned short*)(ws + 39845888);        // 2097152
        unsigned*       mbits   = (unsigned*)(ws + 41943040);              // 1048576

        prep_kernel<<<7172, 256, 0, stream>>>(q_input, mask, w_qkv, w_out, b_out,
                                              qin_bf, wqkv_bt, wout_bt, mbits,
                                              out + (size_t)M_DIM * H_DIM);
        gemm_bt_kernel<128, 128, true, true, true><<<dim3(24, 32), 256, 0, stream>>>(qin_bf, wqkv_bt, b_qkv, qkv, 3072);
        attn_mfma_kernel<<<dim3(16, 32), 512, 0, stream>>>(qkv, mbits, ctx);
        gemm_bt_kernel<64, 128, false, false, false><<<dim3(8, 64), 256, 0, stream>>>(ctx, wout_bt, nullptr, out, 1024);
    } else {
        // R9-proven fallback layout (peak ~40.9 MB), separate prep kernels
        bf16*           qkv     = (bf16*)ws;                               // 25165824
        unsigned short* qin_bf  = (unsigned short*)(ws + 25165824);        // 8388608 (reused as ctx)
        unsigned short* ctx     = qin_bf;
        unsigned short* wqkv_bt = (unsigned short*)(ws + 33554432);        // 6291456 (reused as wout_bt)
        unsigned short* wout_bt = wqkv_bt;
        unsigned*       mbits   = (unsigned*)(ws + 39845888);              // 1048576
        int*            flag    = (int*)(ws + 40894464);                   // 4

        detect_mask_kernel<<<1, 256, 0, stream>>>((const int*)mask, flag);
        pack_mask_kernel<<<1024, 256, 0, stream>>>((const int*)mask, (const unsigned char*)mask, flag, mbits);
        convert_kernel<<<2048, 256, 0, stream>>>(q_input, qin_bf);
        transpose_bf16_kernel<<<dim3(96, 32), 256, 0, stream>>>(w_qkv, wqkv_bt, 1024, 3072);
        gemm_bt_kernel<128, 128, true, true, true><<<dim3(24, 32), 256, 0, stream>>>(qin_bf, wqkv_bt, b_qkv, qkv, 3072);
        transpose_bf16_kernel<<<dim3(32, 32), 256, 0, stream>>>(w_out, wout_bt, 1024, 1024);
        attn_mfma_kernel<<<dim3(16, 32), 512, 0, stream>>>(qkv, mbits, ctx);
        gemm_bt_kernel<64, 128, false, false, false><<<dim3(8, 64), 256, 0, stream>>>(ctx, wout_bt, nullptr, out, 1024);
        bout_copy_kernel<<<4, 256, 0, stream>>>(b_out, out + (size_t)M_DIM * H_DIM);
    }
}

// Round 11
// 227.493 us; speedup vs baseline: 1.0605x; 1.0224x over previous
//
#include <hip/hip_runtime.h>
#include <hip/hip_bf16.h>
#include <math.h>

// Problem constants
#define F_DIM 2048
#define B_DIM 2
#define H_DIM 1024
#define N_HEADS 16
#define E_DIM 64
#define D3 3072          // 3*H
#define M_DIM 4096       // F*B

typedef __hip_bfloat16 bf16;
typedef __attribute__((ext_vector_type(8))) __bf16 bf16x8;
typedef __attribute__((ext_vector_type(8))) unsigned short u16x8;
typedef __attribute__((ext_vector_type(4))) float f32x4;

// float -> bf16 bits, round-to-nearest-even
static __device__ __forceinline__ unsigned short f2bf(float f) {
    unsigned u = __float_as_uint(f);
    return (unsigned short)((u + 0x7FFFu + ((u >> 16) & 1u)) >> 16);
}

// pack two floats to bf16x2 (RNE); HW packed convert when available
static __device__ __forceinline__ unsigned pk_bf16(float a, float b) {
#if __has_builtin(__builtin_amdgcn_cvt_pk_bf16_f32)
    typedef __attribute__((ext_vector_type(2))) __bf16 bf16x2;
    bf16x2 v = __builtin_amdgcn_cvt_pk_bf16_f32(a, b);
    unsigned u; __builtin_memcpy(&u, &v, 4); return u;
#else
    return (unsigned)f2bf(a) | ((unsigned)f2bf(b) << 16);
#endif
}

// async global->LDS, 16B per lane; lds ptr must be wave-uniform base
static __device__ __forceinline__ void glds16(const unsigned short* g, unsigned short* l) {
    __builtin_amdgcn_global_load_lds((const __attribute__((address_space(1))) unsigned int*)g,
                                     (__attribute__((address_space(3))) unsigned int*)l,
                                     16, 0, 0);
}

// 0.125 * log2(e): folded into q at QKV-gemm epilogue so softmax is exp2(S)
#define Q_SCALE 0.18033688011112042f

// ---------------------------------------------------------------------------
// Fused prep (R10-proven)
// ---------------------------------------------------------------------------
__global__ __launch_bounds__(256) void prep_kernel(const float* __restrict__ q_input,
                                                   const void* __restrict__ mask,
                                                   const float* __restrict__ w_qkv,
                                                   const float* __restrict__ w_out,
                                                   const float* __restrict__ b_out,
                                                   unsigned short* __restrict__ qin_bf,
                                                   unsigned short* __restrict__ wqkv_bt,
                                                   unsigned short* __restrict__ wout_bt,
                                                   unsigned* __restrict__ mbits,
                                                   float* __restrict__ bout_dst) {
    __shared__ float sh[32 * 33];
    const int bid = blockIdx.x;
    const int tid = threadIdx.x;

    if (bid < 2048) {                       // convert
        int i = (bid * 256 + tid) * 8;
        float4 a = *(const float4*)&q_input[i];
        float4 b = *(const float4*)&q_input[i + 4];
        u16x8 o;
        o[0] = f2bf(a.x); o[1] = f2bf(a.y); o[2] = f2bf(a.z); o[3] = f2bf(a.w);
        o[4] = f2bf(b.x); o[5] = f2bf(b.y); o[6] = f2bf(b.z); o[7] = f2bf(b.w);
        *(u16x8*)&qin_bf[i] = o;
    } else if (bid < 6144) {                // transposes
        const float* in; unsigned short* out; int R, C, bx, by;
        if (bid < 5120) { int idx = bid - 2048; in = w_qkv; out = wqkv_bt; R = 1024; C = 3072; bx = idx % 96; by = idx / 96; }
        else            { int idx = bid - 5120; in = w_out; out = wout_bt; R = 1024; C = 1024; bx = idx % 32; by = idx / 32; }
        float (*t)[33] = (float(*)[33])sh;
        const int c0 = bx * 32, r0 = by * 32;
        const int lc = tid & 31, lr = tid >> 5;
        #pragma unroll
        for (int i = 0; i < 4; ++i) {
            int r = lr + i * 8;
            t[r][lc] = in[(size_t)(r0 + r) * C + c0 + lc];
        }
        __syncthreads();
        #pragma unroll
        for (int i = 0; i < 4; ++i) {
            int r = lr + i * 8;
            out[(size_t)(c0 + r) * R + r0 + lc] = f2bf(t[lc][r]);
        }
    } else if (bid < 7168) {                // mask pack with inline detect
        int* shi = (int*)sh;
        int v = ((const int*)mask)[tid] & ~1;
        unsigned long long bal = __ballot(v != 0);
        if ((tid & 63) == 0) shi[tid >> 6] = (bal != 0) ? 1 : 0;
        __syncthreads();
        const int byte_mode = shi[0] | shi[1] | shi[2] | shi[3];
        int w = (bid - 6144) * 256 + tid;
        size_t base = (size_t)w * 32;
        unsigned out = 0;
        if (byte_mode) {
            const unsigned char* mu = (const unsigned char*)mask;
            #pragma unroll
            for (int j = 0; j < 32; ++j) out |= (mu[base + j] ? 1u : 0u) << j;
        } else {
            const int* mi = (const int*)mask;
            #pragma unroll
            for (int j = 0; j < 32; ++j) out |= (mi[base + j] ? 1u : 0u) << j;
        }
        mbits[w] = out;
    } else {                                // b_out copy
        int h = (bid - 7168) * 256 + tid;
        if (h < H_DIM) bout_dst[h] = b_out[h];
    }
}

// --------------------- fallback prep kernels (R9-proven) -------------------
__global__ void detect_mask_kernel(const int* __restrict__ mask_words, int* __restrict__ flag) {
    __shared__ int red[256];
    int v = mask_words[threadIdx.x];
    red[threadIdx.x] = v & ~1;
    __syncthreads();
    for (int s = 128; s > 0; s >>= 1) {
        if (threadIdx.x < s) red[threadIdx.x] |= red[threadIdx.x + s];
        __syncthreads();
    }
    if (threadIdx.x == 0) *flag = (red[0] != 0) ? 1 : 0;
}

__global__ void pack_mask_kernel(const int* __restrict__ mi, const unsigned char* __restrict__ mu,
                                 const int* __restrict__ flag, unsigned* __restrict__ bits) {
    int w = blockIdx.x * 256 + threadIdx.x;
    size_t base = (size_t)w * 32;
    unsigned out = 0;
    if (*flag) {
        #pragma unroll
        for (int j = 0; j < 32; ++j) out |= (mu[base + j] ? 1u : 0u) << j;
    } else {
        #pragma unroll
        for (int j = 0; j < 32; ++j) out |= (mi[base + j] ? 1u : 0u) << j;
    }
    bits[w] = out;
}

__global__ __launch_bounds__(256) void convert_kernel(const float* __restrict__ in,
                                                      unsigned short* __restrict__ out) {
    int i = (blockIdx.x * 256 + threadIdx.x) * 8;
    float4 a = *(const float4*)&in[i];
    float4 b = *(const float4*)&in[i + 4];
    u16x8 o;
    o[0] = f2bf(a.x); o[1] = f2bf(a.y); o[2] = f2bf(a.z); o[3] = f2bf(a.w);
    o[4] = f2bf(b.x); o[5] = f2bf(b.y); o[6] = f2bf(b.z); o[7] = f2bf(b.w);
    *(u16x8*)&out[i] = o;
}

__global__ __launch_bounds__(256) void transpose_bf16_kernel(const float* __restrict__ in,
                                                             unsigned short* __restrict__ out,
                                                             int R, int C) {
    __shared__ float t[32][33];
    const int c0 = blockIdx.x * 32, r0 = blockIdx.y * 32;
    const int lc = threadIdx.x & 31, lr = threadIdx.x >> 5;
    #pragma unroll
    for (int i = 0; i < 4; ++i) {
        int r = lr + i * 8;
        t[r][lc] = in[(size_t)(r0 + r) * C + c0 + lc];
    }
    __syncthreads();
    #pragma unroll
    for (int i = 0; i < 4; ++i) {
        int r = lr + i * 8;
        out[(size_t)(c0 + r) * R + r0 + lc] = f2bf(t[lc][r]);
    }
}

__global__ void bout_copy_kernel(const float* __restrict__ b_out, float* __restrict__ dst) {
    int h = blockIdx.x * 256 + threadIdx.x;
    if (h < H_DIM) dst[h] = b_out[h];
}

// ---------------------------------------------------------------------------
// m97-style bf16 MFMA GEMM, B-transposed input, tile BM x BN (mult of 64).
// SCALE_Q: multiply q-columns (col%192 < 64) by Q_SCALE in the epilogue
// (folds the attention 1/sqrt(E) and log2(e) into Q once).
// ---------------------------------------------------------------------------
template<int BM, int BN, bool ADD_BIAS, bool OUT_BF16, bool SCALE_Q>
__global__ __launch_bounds__(256) void gemm_bt_kernel(const unsigned short* __restrict__ A,
                                                      const unsigned short* __restrict__ Bt,
                                                      const float* __restrict__ bias,
                                                      void* __restrict__ Cout, int Nc) {
    __shared__ unsigned short Ald[BM * 32];
    __shared__ unsigned short Bld[BN * 32];
    constexpr int WM = BM / 2, WN = BN / 2;
    constexpr int MI = WM / 16, NI = WN / 16;
    constexpr int ACH = BM * 4;
    constexpr int TCH = (BM + BN) * 4;
    const int tid = threadIdx.x;
    const int wave = tid >> 6;
    const int lane = tid & 63;
    const int quad = lane >> 4;
    const int l16 = lane & 15;
    const int wm = (wave & 1) * WM;
    const int wn = (wave >> 1) * WN;
    const int m0 = blockIdx.y * BM;
    const int n0 = blockIdx.x * BN;

    f32x4 acc[MI][NI];
    #pragma unroll
    for (int i = 0; i < MI; ++i)
        #pragma unroll
        for (int j = 0; j < NI; ++j) acc[i][j] = (f32x4){0.f, 0.f, 0.f, 0.f};

    for (int k0 = 0; k0 < 1024; k0 += 32) {
        __syncthreads();
        #pragma unroll
        for (int rr = 0; rr < TCH / 256; ++rr) {
            const int chunk = rr * 256 + tid;
            const int wbase = (rr * 256 + wave * 64) * 8;
            if (chunk < ACH) {
                const int row = chunk >> 2, ko = (chunk & 3) * 8;
                glds16(&A[(size_t)(m0 + row) * 1024 + k0 + ko], &Ald[wbase]);
            } else {
                const int c2 = chunk - ACH;
                const int row = c2 >> 2, ko = (c2 & 3) * 8;
                glds16(&Bt[(size_t)(n0 + row) * 1024 + k0 + ko], &Bld[wbase - ACH * 8]);
            }
        }
        __syncthreads();

        bf16x8 af[MI], bfr[NI];
        #pragma unroll
        for (int i = 0; i < MI; ++i)
            af[i] = *(const bf16x8*)&Ald[(wm + i * 16 + l16) * 32 + quad * 8];
        #pragma unroll
        for (int j = 0; j < NI; ++j)
            bfr[j] = *(const bf16x8*)&Bld[(wn + j * 16 + l16) * 32 + quad * 8];
        #pragma unroll
        for (int mi = 0; mi < MI; ++mi)
            #pragma unroll
            for (int ni = 0; ni < NI; ++ni)
                acc[mi][ni] = __builtin_amdgcn_mfma_f32_16x16x32_bf16(af[mi], bfr[ni], acc[mi][ni], 0, 0, 0);
    }

    #pragma unroll
    for (int ni = 0; ni < NI; ++ni) {
        const int col = n0 + wn + ni * 16 + l16;
        const float bv = ADD_BIAS ? bias[col] : 0.f;
        const bool scale = SCALE_Q && ((col % 192) < 64);
        #pragma unroll
        for (int mi = 0; mi < MI; ++mi) {
            const int rowb = m0 + wm + mi * 16 + quad * 4;
            #pragma unroll
            for (int r = 0; r < 4; ++r) {
                float v = acc[mi][ni][r] + bv;
                if (SCALE_Q) v = scale ? v * Q_SCALE : v;
                if (OUT_BF16) ((unsigned short*)Cout)[(size_t)(rowb + r) * Nc + col] = f2bf(v);
                else          ((float*)Cout)[(size_t)(rowb + r) * Nc + col] = v;
            }
        }
    }
}

// ---------------------------------------------------------------------------
// MFMA flash attention. R17: ping-pong index p derived from t0 + #pragma
// unroll 2 -> p is compile-time in each unrolled copy, so buffer base folds
// into ds offset immediates and LICM hoists the ~30-60 per-iteration swz()
// address VALU ops (R16 profile: VALUBusy 52% vs MfmaUtil 18%, VGPR only 56
// => compiler recomputed addresses every iter instead of hoisting).
// R16 single-barrier ping-pong + T14 reg prefetch + R14 swizzle retained;
// no sync or arithmetic change.
// ---------------------------------------------------------------------------
static __device__ __forceinline__ int swz(int row, int elem) {
    return row * 64 + (elem ^ ((row & 7) << 3));
}

__global__ __launch_bounds__(512, 4) void attn_mfma_kernel(const bf16* __restrict__ qkv_,
                                                           const unsigned* __restrict__ mbits,
                                                           unsigned short* __restrict__ ctxb) {
    __shared__ unsigned short K_lds[2][64 * 64];       // [buf][t][e]      2x8192 B
    __shared__ unsigned short Vt_lds[2][64 * 64];      // [buf][e][slot]   2x8192 B
    __shared__ unsigned short P_lds[128 * 64];         // [row][slot]      16384 B

    const unsigned short* qkv = (const unsigned short*)qkv_;
    const int tid = threadIdx.x;
    const int wave = tid >> 6;          // 0..7
    const int lane = tid & 63;
    const int quad = lane >> 4;
    const int l16 = lane & 15;
    const int f0 = blockIdx.x * 128;
    const int b = blockIdx.y >> 4;
    const int n = blockIdx.y & 15;
    const int head = n * 192;

    // Q fragments [ks] (A layout): rows f0 + wave*16 + l16 (pre-scaled)
    bf16x8 qf[2];
    #pragma unroll
    for (int ks = 0; ks < 2; ++ks) {
        int f = f0 + wave * 16 + l16;
        qf[ks] = *(const bf16x8*)&qkv[(size_t)(f * B_DIM + b) * D3 + head + ks * 32 + quad * 8];
    }

    f32x4 O[4];
    #pragma unroll
    for (int ec = 0; ec < 4; ++ec) O[ec] = (f32x4){0.f, 0.f, 0.f, 0.f};
    float lsum[4] = {0.f, 0.f, 0.f, 0.f};

    unsigned short* Pw = P_lds + wave * 16 * 64;
    // loop-invariant mask row base: rows f0 + wave*16 + quad*4 + r, stride 64 words/row
    const unsigned* mrow = &mbits[((size_t)b * F_DIM + (f0 + wave * 16 + quad * 4)) * 64];

    // ---- staging-address invariants ----
    const int ktr = tid >> 3, ke0 = (tid & 7) * 8;      // K: row, elem base
    const int vu = tid & 15, vh = (tid >> 4) & 1, ve0 = (tid >> 5) * 8;  // V (tid<256)
    const unsigned short* kbase = &qkv[(size_t)((size_t)ktr * B_DIM + b) * D3 + head + 64 + ke0];
    const unsigned short* vbase0 = &qkv[(size_t)((size_t)(vh * 32 + vu) * B_DIM + b) * D3 + head + 128 + ve0];
    const unsigned short* vbase1 = vbase0 + (size_t)16 * B_DIM * D3;
    const size_t tstride = (size_t)B_DIM * D3;          // per-t-row elements

    // ---- prefetch registers ----
    u16x8 kreg, vreg0, vreg1;

    // prologue: issue loads for tile 0
    kreg = *(const u16x8*)&kbase[0];
    if (tid < 256) {
        vreg0 = *(const u16x8*)&vbase0[0];
        vreg1 = *(const u16x8*)&vbase1[0];
    }

    #pragma unroll 2
    for (int t0 = 0; t0 < F_DIM; t0 += 64) {
        const int p = (t0 >> 6) & 1;      // compile-time per unrolled copy

        // write staged registers to LDS buf[p] (swizzled); no barrier needed
        // before: buf[p]'s prior readers drained at the previous iteration's
        // barrier (R16 race matrix).
        *(u16x8*)&K_lds[p][swz(ktr, ke0)] = kreg;
        if (tid < 256) {
            #pragma unroll
            for (int j = 0; j < 8; ++j) {
                unsigned pk = (unsigned)vreg0[j] | ((unsigned)vreg1[j] << 16);
                *(unsigned*)&Vt_lds[p][swz(ve0 + j, vh * 32 + 2 * vu)] = pk;
            }
        }
        __syncthreads();   // staging visible; prev iteration's reads drained

        // issue next tile's loads now -> latency hides under compute below
        {
            int tn = (t0 + 64 < F_DIM) ? (t0 + 64) : t0;   // clamp (values unused last iter)
            kreg = *(const u16x8*)&kbase[(size_t)tn * tstride];
            if (tid < 256) {
                vreg0 = *(const u16x8*)&vbase0[(size_t)tn * tstride];
                vreg1 = *(const u16x8*)&vbase1[(size_t)tn * tstride];
            }
        }

        // S = Q . K^T  [16 x 64] per wave; S[ck] covers t = ck*16 + l16
        f32x4 S[4];
        #pragma unroll
        for (int ck = 0; ck < 4; ++ck) S[ck] = (f32x4){0.f, 0.f, 0.f, 0.f};
        __builtin_amdgcn_s_setprio(1);
        #pragma unroll
        for (int ck = 0; ck < 4; ++ck) {
            bf16x8 kb0 = *(const bf16x8*)&K_lds[p][swz(ck * 16 + l16, quad * 8)];
            bf16x8 kb1 = *(const bf16x8*)&K_lds[p][swz(ck * 16 + l16, 32 + quad * 8)];
            S[ck] = __builtin_amdgcn_mfma_f32_16x16x32_bf16(qf[0], kb0, S[ck], 0, 0, 0);
            S[ck] = __builtin_amdgcn_mfma_f32_16x16x32_bf16(qf[1], kb1, S[ck], 0, 0, 0);
        }
        __builtin_amdgcn_s_setprio(0);

        // batch the 4 mask uint2 loads, then softmax.
        uint2 wbv[4];
        #pragma unroll
        for (int r = 0; r < 4; ++r)
            wbv[r] = *(const uint2*)&mrow[(size_t)r * 64 + (t0 >> 5)];

        // fixed-max softmax: p = mask ? exp2(S) : 0 (scale folded into Q);
        // packed P writes: (p0,p1) -> slots (2*l16, 2*l16+1); (p2,p3) -> +32.
        #pragma unroll
        for (int r = 0; r < 4; ++r) {
            const int row = quad * 4 + r;            // within wave's 16 rows
            float pv4[4];
            #pragma unroll
            for (int ck = 0; ck < 4; ++ck) {
                unsigned wsel = (ck & 2) ? wbv[r].y : wbv[r].x;
                int bit = ((ck & 1) << 4) + l16;
                float pv = __builtin_amdgcn_exp2f(S[ck][r]);
                pv4[ck] = ((wsel >> bit) & 1u) ? pv : 0.f;
            }
            lsum[r] += (pv4[0] + pv4[1]) + (pv4[2] + pv4[3]);
            *(unsigned*)&Pw[swz(row, 2 * l16)] = pk_bf16(pv4[0], pv4[1]);
            *(unsigned*)&Pw[swz(row, 32 + 2 * l16)] = pk_bf16(pv4[2], pv4[3]);
        }

        // O += P . V  (both operands traverse slots in identical order).
        // P is wave-private: lgkmcnt ordering within the wave suffices.
        __builtin_amdgcn_s_setprio(1);
        #pragma unroll
        for (int ks = 0; ks < 2; ++ks) {
            bf16x8 pa = *(const bf16x8*)&Pw[swz(l16, ks * 32 + quad * 8)];
            #pragma unroll
            for (int ec = 0; ec < 4; ++ec) {
                bf16x8 vb = *(const bf16x8*)&Vt_lds[p][swz(ec * 16 + l16, ks * 32 + quad * 8)];
                O[ec] = __builtin_amdgcn_mfma_f32_16x16x32_bf16(pa, vb, O[ec], 0, 0, 0);
            }
        }
        __builtin_amdgcn_s_setprio(0);
    }

    // epilogue: reduce l over the 16 lanes sharing each row, write ctx (bf16)
    #pragma unroll
    for (int r = 0; r < 4; ++r) {
        float l = lsum[r];
        #pragma unroll
        for (int d = 1; d < 16; d <<= 1) l += __shfl_xor(l, d);
        const int f = f0 + wave * 16 + quad * 4 + r;
        const float inv = 1.0f / l;
        #pragma unroll
        for (int ec = 0; ec < 4; ++ec) {
            ctxb[(size_t)(f * B_DIM + b) * H_DIM + n * 64 + ec * 16 + l16] = f2bf(O[ec][r] * inv);
        }
    }
}

// ---------------------------------------------------------------------------
extern "C" void kernel_launch(void* const* d_in, const int* in_sizes, int n_in,
                              void* d_out, int out_size, void* d_ws, size_t ws_size,
                              hipStream_t stream) {
    const float* q_input = (const float*)d_in[0];
    const void*  mask    = d_in[1];
    const float* w_qkv   = (const float*)d_in[2];
    const float* b_qkv   = (const float*)d_in[3];
    const float* w_out   = (const float*)d_in[4];
    const float* b_out   = (const float*)d_in[5];
    float* out = (float*)d_out;
    char* ws = (char*)d_ws;

    const size_t FUSED_WS = 42991616;   // through mbits

    if (ws_size >= FUSED_WS) {
        bf16*           qkv     = (bf16*)ws;                               // 25165824
        unsigned short* qin_bf  = (unsigned short*)(ws + 25165824);        // 8388608 (reused as ctx)
        unsigned short* ctx     = qin_bf;
        unsigned short* wqkv_bt = (unsigned short*)(ws + 33554432);        // 6291456
        unsigned short* wout_bt = (unsigned short*)(ws + 39845888);        // 2097152
        unsigned*       mbits   = (unsigned*)(ws + 41943040);              // 1048576

        prep_kernel<<<7172, 256, 0, stream>>>(q_input, mask, w_qkv, w_out, b_out,
                                              qin_bf, wqkv_bt, wout_bt, mbits,
                                              out + (size_t)M_DIM * H_DIM);
        gemm_bt_kernel<128, 128, true, true, true><<<dim3(24, 32), 256, 0, stream>>>(qin_bf, wqkv_bt, b_qkv, qkv, 3072);
        attn_mfma_kernel<<<dim3(16, 32), 512, 0, stream>>>(qkv, mbits, ctx);
        gemm_bt_kernel<64, 128, false, false, false><<<dim3(8, 64), 256, 0, stream>>>(ctx, wout_bt, nullptr, out, 1024);
    } else {
        // R9-proven fallback layout (peak ~40.9 MB), separate prep kernels
        bf16*           qkv     = (bf16*)ws;                               // 25165824
        unsigned short* qin_bf  = (unsigned short*)(ws + 25165824);        // 8388608 (reused as ctx)
        unsigned short* ctx     = qin_bf;
        unsigned short* wqkv_bt = (unsigned short*)(ws + 33554432);        // 6291456 (reused as wout_bt)
        unsigned short* wout_bt = wqkv_bt;
        unsigned*       mbits   = (unsigned*)(ws + 39845888);              // 1048576
        int*            flag    = (int*)(ws + 40894464);                   // 4

        detect_mask_kernel<<<1, 256, 0, stream>>>((const int*)mask, flag);
        pack_mask_kernel<<<1024, 256, 0, stream>>>((const int*)mask, (const unsigned char*)mask, flag, mbits);
        convert_kernel<<<2048, 256, 0, stream>>>(q_input, qin_bf);
        transpose_bf16_kernel<<<dim3(96, 32), 256, 0, stream>>>(w_qkv, wqkv_bt, 1024, 3072);
        gemm_bt_kernel<128, 128, true, true, true><<<dim3(24, 32), 256, 0, stream>>>(qin_bf, wqkv_bt, b_qkv, qkv, 3072);
        transpose_bf16_kernel<<<dim3(32, 32), 256, 0, stream>>>(w_out, wout_bt, 1024, 1024);
        attn_mfma_kernel<<<dim3(16, 32), 512, 0, stream>>>(qkv, mbits, ctx);
        gemm_bt_kernel<64, 128, false, false, false><<<dim3(8, 64), 256, 0, stream>>>(ctx, wout_bt, nullptr, out, 1024);
        bout_copy_kernel<<<4, 256, 0, stream>>>(b_out, out + (size_t)M_DIM * H_DIM);
    }
}